// Round 1
// baseline (901.050 us; speedup 1.0000x reference)
//
#include <hip/hip_runtime.h>
#include <math.h>

#define NNODES 62
#define NDEG 8
#define NGRAPH 800
#define NB 16
#define NT 50
#define NIN 64
#define NCH 128
#define NH 256
#define NCLS 3
#define NTOPK 5
#define EPG (NNODES*NDEG)       // 496 edges per graph
#define E2G (EPG + NNODES)      // 558 incl self loops
#define NTOTAL (NGRAPH*NNODES)  // 49600
#define ETOTAL (NGRAPH*EPG)     // 396800

// ---------------- xr = x @ W_r + b_r (thread computes 4 consecutive channels) ----------------
__global__ void k_xr(const float* __restrict__ x, const float* __restrict__ W_r,
                     const float* __restrict__ b_r, float* __restrict__ xr) {
    int idx = blockIdx.x * blockDim.x + threadIdx.x;   // over NTOTAL*32
    if (idx >= NTOTAL * 32) return;
    int v = idx >> 5;
    int c4 = (idx & 31) * 4;
    const float* xrow = x + (size_t)v * NIN;
    float4 acc = make_float4(b_r[c4], b_r[c4 + 1], b_r[c4 + 2], b_r[c4 + 3]);
    for (int k = 0; k < NIN; ++k) {
        float xv = xrow[k];
        float4 w = *reinterpret_cast<const float4*>(W_r + k * NCH + c4);
        acc.x += xv * w.x; acc.y += xv * w.y; acc.z += xv * w.z; acc.w += xv * w.w;
    }
    *reinterpret_cast<float4*>(xr + (size_t)v * NCH + c4) = acc;
}

// ---------------- simple transpose ----------------
__global__ void k_transpose(const float* __restrict__ src, float* __restrict__ dst,
                            int rows, int cols) {
    int idx = blockIdx.x * blockDim.x + threadIdx.x;
    if (idx >= rows * cols) return;
    int r = idx / cols;
    int c = idx - r * cols;
    dst[c * rows + r] = src[idx];
}

// ---------------- fused per-graph GATv2 + mean pool ----------------
__launch_bounds__(256)
__global__ void k_gat(const float* __restrict__ x, const int* __restrict__ ei,
                      const float* __restrict__ eattr,
                      const float* __restrict__ W_l, const float* __restrict__ b_l,
                      const float* __restrict__ W_e, const float* __restrict__ att,
                      const float* __restrict__ bias_out,
                      const float* __restrict__ xr_all, float* __restrict__ g_all) {
    __shared__ float x_s[NNODES * NIN];       // 15872 B
    __shared__ float xl_s[NNODES * NCH];      // 31744 B
    __shared__ float e_s[E2G];                // 2232 B
    __shared__ unsigned emax_s[NNODES];
    __shared__ float den_s[NNODES];
    __shared__ float la_s[NNODES];
    __shared__ float cnt_s[NNODES];
    __shared__ float sum_s[NNODES];
    __shared__ unsigned short sd_s[EPG];      // src | dst<<6
    __shared__ float attr_s[EPG];
    __shared__ float gacc_s[4 * NCH];         // per-wave pooled accumulators

    const int g = blockIdx.x;
    const int tid = threadIdx.x;
    const int base_e = g * EPG;
    const int base_n = g * NNODES;

    for (int v = tid; v < NNODES; v += 256) {
        sum_s[v] = 0.f; cnt_s[v] = 0.f; emax_s[v] = 0u; den_s[v] = 0.f;
    }
    for (int j = tid; j < EPG; j += 256) {
        int s = ei[base_e + j] - base_n;
        int d = ei[ETOTAL + base_e + j] - base_n;
        sd_s[j] = (unsigned short)(s | (d << 6));
        attr_s[j] = eattr[base_e + j];
    }
    for (int i = tid; i < NNODES * NIN; i += 256) x_s[i] = x[(size_t)base_n * NIN + i];
    __syncthreads();

    // self-loop edge_attr = mean of incoming edge_attr
    for (int j = tid; j < EPG; j += 256) {
        int d = sd_s[j] >> 6;
        atomicAdd(&sum_s[d], attr_s[j]);
        atomicAdd(&cnt_s[d], 1.f);
    }
    __syncthreads();
    for (int v = tid; v < NNODES; v += 256) la_s[v] = sum_s[v] / fmaxf(cnt_s[v], 1.f);

    // xl = x @ W_l + b_l (in LDS)
    for (int i = tid; i < NNODES * NCH; i += 256) {
        int v = i >> 7;
        int c = i & (NCH - 1);
        float acc = b_l[c];
        const float* xrow = x_s + v * NIN;
        for (int k = 0; k < NIN; ++k) acc += xrow[k] * W_l[k * NCH + c];
        xl_s[i] = acc;
    }
    __syncthreads();

    const int wave = tid >> 6;
    const int lane = tid & 63;

    // P1: per-edge attention logits e, running max per dst (ordered-uint atomicMax)
    for (int j = wave; j < E2G; j += 4) {
        int s, d; float a;
        if (j < EPG) { int sd = sd_s[j]; s = sd & 63; d = sd >> 6; a = attr_s[j]; }
        else { s = d = j - EPG; a = la_s[s]; }
        const float* xrrow = xr_all + (size_t)(base_n + d) * NCH;
        int c0 = lane, c1 = lane + 64;
        float m0 = xl_s[s * NCH + c0] + xrrow[c0] + a * W_e[c0];
        float m1 = xl_s[s * NCH + c1] + xrrow[c1] + a * W_e[c1];
        float t = (m0 >= 0.f ? m0 : 0.2f * m0) * att[c0]
                + (m1 >= 0.f ? m1 : 0.2f * m1) * att[c1];
        for (int off = 32; off > 0; off >>= 1) t += __shfl_xor(t, off, 64);
        if (lane == 0) {
            e_s[j] = t;
            unsigned u = __float_as_uint(t);
            unsigned key = (u & 0x80000000u) ? ~u : (u | 0x80000000u);
            atomicMax(&emax_s[d], key);
        }
    }
    __syncthreads();

    // denominator of scatter-softmax
    for (int j = tid; j < E2G; j += 256) {
        int d = (j < EPG) ? (sd_s[j] >> 6) : (j - EPG);
        unsigned key = emax_s[d];
        float mx = __uint_as_float((key & 0x80000000u) ? (key & 0x7fffffffu) : ~key);
        atomicAdd(&den_s[d], expf(e_s[j] - mx));
    }
    __syncthreads();

    // P2: pooled aggregate over all edges (mean-pool commutes with segment_sum)
    float acc0 = 0.f, acc1 = 0.f;
    for (int j = wave; j < E2G; j += 4) {
        int s, d;
        if (j < EPG) { int sd = sd_s[j]; s = sd & 63; d = sd >> 6; }
        else { s = d = j - EPG; }
        unsigned key = emax_s[d];
        float mx = __uint_as_float((key & 0x80000000u) ? (key & 0x7fffffffu) : ~key);
        float alpha = expf(e_s[j] - mx) / den_s[d];
        acc0 += alpha * xl_s[s * NCH + lane];
        acc1 += alpha * xl_s[s * NCH + lane + 64];
    }
    gacc_s[wave * NCH + lane] = acc0;
    gacc_s[wave * NCH + lane + 64] = acc1;
    __syncthreads();

    for (int c = tid; c < NCH; c += 256) {
        float v = (gacc_s[c] + gacc_s[NCH + c] + gacc_s[2 * NCH + c] + gacc_s[3 * NCH + c])
                      * (1.f / NNODES) + bias_out[c];
        g_all[(size_t)g * NCH + c] = v;
    }
}

// ---------------- gx_all = g_all @ W_ih^T + b_ih ----------------
__global__ void k_gx(const float* __restrict__ g_all, const float* __restrict__ W_ihT,
                     const float* __restrict__ b_ih, float* __restrict__ gx_all) {
    int idx = blockIdx.x * blockDim.x + threadIdx.x;   // over 800*768
    if (idx >= NGRAPH * 3 * NH) return;
    int gi = idx / (3 * NH);
    int o = idx - gi * (3 * NH);
    float acc = b_ih[o];
    const float* grow = g_all + (size_t)gi * NCH;
    for (int c = 0; c < NCH; ++c) acc += grow[c] * W_ihT[c * (3 * NH) + o];
    gx_all[idx] = acc;
}

// ---------------- GRU (sequential) + classifier + top-k ----------------
__launch_bounds__(768)
__global__ void k_gru(const float* __restrict__ gx_all, const float* __restrict__ W_hhT,
                      const float* __restrict__ b_hh,
                      const float* __restrict__ W1, const float* __restrict__ b1,
                      const float* __restrict__ W2, const float* __restrict__ b2,
                      float* __restrict__ out) {
    __shared__ float h_s[2][NH];
    __shared__ float gh_s[3 * NH];
    __shared__ float s1_s[NH / 2];
    __shared__ float sc_s[NT * NCLS];

    const int b = blockIdx.x;
    const int tid = threadIdx.x;

    for (int i = tid; i < NH; i += 768) h_s[0][i] = 0.f;
    __syncthreads();

    int cur = 0;
    for (int t = 0; t < NT; ++t) {
        // gh = h @ W_hh^T + b_hh  (768 outputs, one per thread)
        {
            float acc = b_hh[tid];
            const float* h = h_s[cur];
            for (int k = 0; k < NH; ++k) acc += h[k] * W_hhT[k * (3 * NH) + tid];
            gh_s[tid] = acc;
        }
        __syncthreads();
        if (tid < NH) {
            const float* gx = gx_all + (size_t)(b * NT + t) * (3 * NH);
            float r = 1.f / (1.f + expf(-(gx[tid] + gh_s[tid])));
            float z = 1.f / (1.f + expf(-(gx[tid + NH] + gh_s[tid + NH])));
            float n = tanhf(gx[tid + 2 * NH] + r * gh_s[tid + 2 * NH]);
            h_s[cur ^ 1][tid] = (1.f - z) * n + z * h_s[cur][tid];
        }
        __syncthreads();
        cur ^= 1;
        // classifier: s1 = relu(h @ W1 + b1); scores = s1 @ W2 + b2
        if (tid < NH / 2) {
            float acc = b1[tid];
            const float* h = h_s[cur];
            for (int k = 0; k < NH; ++k) acc += h[k] * W1[k * (NH / 2) + tid];
            s1_s[tid] = fmaxf(acc, 0.f);
        }
        __syncthreads();
        if (tid < NCLS) {
            float acc = b2[tid];
            for (int k = 0; k < NH / 2; ++k) acc += s1_s[k] * W2[k * NCLS + tid];
            sc_s[t * NCLS + tid] = acc;
        }
        __syncthreads();
    }

    // exact top-k over time per class (strict >, first index wins == lax.top_k)
    if (tid < NCLS) {
        int c = tid;
        float vals[NT];
        for (int t = 0; t < NT; ++t) vals[t] = sc_s[t * NCLS + c];
        float sum = 0.f;
        for (int k = 0; k < NTOPK; ++k) {
            float best = -INFINITY; int bi = 0;
            for (int t = 0; t < NT; ++t) {
                if (vals[t] > best) { best = vals[t]; bi = t; }
            }
            vals[bi] = -INFINITY;
            sum += best;
            out[NB * NCLS + b * (NTOPK * NCLS) + k * NCLS + c] = (float)bi;
        }
        out[b * NCLS + c] = sum * (1.f / NTOPK);
    }
}

extern "C" void kernel_launch(void* const* d_in, const int* in_sizes, int n_in,
                              void* d_out, int out_size, void* d_ws, size_t ws_size,
                              hipStream_t stream) {
    const float* x        = (const float*)d_in[0];
    const int*   ei       = (const int*)  d_in[1];
    const float* eattr    = (const float*)d_in[2];
    const float* W_l      = (const float*)d_in[3];
    const float* b_l      = (const float*)d_in[4];
    const float* W_r      = (const float*)d_in[5];
    const float* b_r      = (const float*)d_in[6];
    const float* W_e      = (const float*)d_in[7];
    const float* att      = (const float*)d_in[8];
    const float* bias_out = (const float*)d_in[9];
    const float* W_ih     = (const float*)d_in[10];
    const float* W_hh     = (const float*)d_in[11];
    const float* b_ih     = (const float*)d_in[12];
    const float* b_hh     = (const float*)d_in[13];
    const float* W1       = (const float*)d_in[14];
    const float* b1       = (const float*)d_in[15];
    const float* W2       = (const float*)d_in[16];
    const float* b2       = (const float*)d_in[17];
    float* out = (float*)d_out;

    float* ws = (float*)d_ws;
    float* xr_all = ws;                                   // 49600*128
    float* g_all  = xr_all + (size_t)NTOTAL * NCH;        // 800*128
    float* gx_all = g_all + NGRAPH * NCH;                 // 800*768
    float* W_ihT  = gx_all + NGRAPH * 3 * NH;             // 128*768
    float* W_hhT  = W_ihT + NCH * 3 * NH;                 // 256*768

    int total_xr = NTOTAL * 32;
    k_xr<<<(total_xr + 255) / 256, 256, 0, stream>>>(x, W_r, b_r, xr_all);
    k_transpose<<<(3 * NH * NCH + 255) / 256, 256, 0, stream>>>(W_ih, W_ihT, 3 * NH, NCH);
    k_transpose<<<(3 * NH * NH + 255) / 256, 256, 0, stream>>>(W_hh, W_hhT, 3 * NH, NH);
    k_gat<<<NGRAPH, 256, 0, stream>>>(x, ei, eattr, W_l, b_l, W_e, att, bias_out, xr_all, g_all);
    k_gx<<<(NGRAPH * 3 * NH + 255) / 256, 256, 0, stream>>>(g_all, W_ihT, b_ih, gx_all);
    k_gru<<<NB, 768, 0, stream>>>(gx_all, W_hhT, b_hh, W1, b1, W2, b2, out);
}

// Round 2
// 649.395 us; speedup vs baseline: 1.3875x; 1.3875x over previous
//
#include <hip/hip_runtime.h>
#include <math.h>

#define NNODES 62
#define NDEG 8
#define NGRAPH 800
#define NB 16
#define NT 50
#define NIN 64
#define NCH 128
#define NH 256
#define NCLS 3
#define NTOPK 5
#define EPG (NNODES*NDEG)       // 496 edges per graph
#define E2G (EPG + NNODES)      // 558 incl self loops
#define NTOTAL (NGRAPH*NNODES)  // 49600
#define ETOTAL (NGRAPH*EPG)     // 396800

// ---------------- xr = x @ W_r + b_r (thread computes 4 consecutive channels) ----------------
__global__ void k_xr(const float* __restrict__ x, const float* __restrict__ W_r,
                     const float* __restrict__ b_r, float* __restrict__ xr) {
    int idx = blockIdx.x * blockDim.x + threadIdx.x;   // over NTOTAL*32
    if (idx >= NTOTAL * 32) return;
    int v = idx >> 5;
    int c4 = (idx & 31) * 4;
    const float* xrow = x + (size_t)v * NIN;
    float4 acc = make_float4(b_r[c4], b_r[c4 + 1], b_r[c4 + 2], b_r[c4 + 3]);
    for (int k = 0; k < NIN; ++k) {
        float xv = xrow[k];
        float4 w = *reinterpret_cast<const float4*>(W_r + k * NCH + c4);
        acc.x += xv * w.x; acc.y += xv * w.y; acc.z += xv * w.z; acc.w += xv * w.w;
    }
    *reinterpret_cast<float4*>(xr + (size_t)v * NCH + c4) = acc;
}

// ---------------- simple transpose ----------------
__global__ void k_transpose(const float* __restrict__ src, float* __restrict__ dst,
                            int rows, int cols) {
    int idx = blockIdx.x * blockDim.x + threadIdx.x;
    if (idx >= rows * cols) return;
    int r = idx / cols;
    int c = idx - r * cols;
    dst[c * rows + r] = src[idx];
}

// ---------------- fused per-graph GATv2 + mean pool ----------------
__launch_bounds__(256)
__global__ void k_gat(const float* __restrict__ x, const int* __restrict__ ei,
                      const float* __restrict__ eattr,
                      const float* __restrict__ W_l, const float* __restrict__ b_l,
                      const float* __restrict__ W_e, const float* __restrict__ att,
                      const float* __restrict__ bias_out,
                      const float* __restrict__ xr_all, float* __restrict__ g_all) {
    __shared__ float x_s[NNODES * NIN];       // 15872 B
    __shared__ float xl_s[NNODES * NCH];      // 31744 B
    __shared__ float e_s[E2G];                // 2232 B
    __shared__ unsigned emax_s[NNODES];
    __shared__ float den_s[NNODES];
    __shared__ float la_s[NNODES];
    __shared__ float cnt_s[NNODES];
    __shared__ float sum_s[NNODES];
    __shared__ unsigned short sd_s[EPG];      // src | dst<<6
    __shared__ float attr_s[EPG];
    __shared__ float gacc_s[4 * NCH];         // per-wave pooled accumulators

    const int g = blockIdx.x;
    const int tid = threadIdx.x;
    const int base_e = g * EPG;
    const int base_n = g * NNODES;

    for (int v = tid; v < NNODES; v += 256) {
        sum_s[v] = 0.f; cnt_s[v] = 0.f; emax_s[v] = 0u; den_s[v] = 0.f;
    }
    for (int j = tid; j < EPG; j += 256) {
        int s = ei[base_e + j] - base_n;
        int d = ei[ETOTAL + base_e + j] - base_n;
        sd_s[j] = (unsigned short)(s | (d << 6));
        attr_s[j] = eattr[base_e + j];
    }
    for (int i = tid; i < NNODES * NIN; i += 256) x_s[i] = x[(size_t)base_n * NIN + i];
    __syncthreads();

    // self-loop edge_attr = mean of incoming edge_attr
    for (int j = tid; j < EPG; j += 256) {
        int d = sd_s[j] >> 6;
        atomicAdd(&sum_s[d], attr_s[j]);
        atomicAdd(&cnt_s[d], 1.f);
    }
    __syncthreads();
    for (int v = tid; v < NNODES; v += 256) la_s[v] = sum_s[v] / fmaxf(cnt_s[v], 1.f);

    // xl = x @ W_l + b_l (in LDS)
    for (int i = tid; i < NNODES * NCH; i += 256) {
        int v = i >> 7;
        int c = i & (NCH - 1);
        float acc = b_l[c];
        const float* xrow = x_s + v * NIN;
        for (int k = 0; k < NIN; ++k) acc += xrow[k] * W_l[k * NCH + c];
        xl_s[i] = acc;
    }
    __syncthreads();

    const int wave = tid >> 6;
    const int lane = tid & 63;

    // P1: per-edge attention logits e, running max per dst (ordered-uint atomicMax)
    for (int j = wave; j < E2G; j += 4) {
        int s, d; float a;
        if (j < EPG) { int sd = sd_s[j]; s = sd & 63; d = sd >> 6; a = attr_s[j]; }
        else { s = d = j - EPG; a = la_s[s]; }
        const float* xrrow = xr_all + (size_t)(base_n + d) * NCH;
        int c0 = lane, c1 = lane + 64;
        float m0 = xl_s[s * NCH + c0] + xrrow[c0] + a * W_e[c0];
        float m1 = xl_s[s * NCH + c1] + xrrow[c1] + a * W_e[c1];
        float t = (m0 >= 0.f ? m0 : 0.2f * m0) * att[c0]
                + (m1 >= 0.f ? m1 : 0.2f * m1) * att[c1];
        for (int off = 32; off > 0; off >>= 1) t += __shfl_xor(t, off, 64);
        if (lane == 0) {
            e_s[j] = t;
            unsigned u = __float_as_uint(t);
            unsigned key = (u & 0x80000000u) ? ~u : (u | 0x80000000u);
            atomicMax(&emax_s[d], key);
        }
    }
    __syncthreads();

    // denominator of scatter-softmax
    for (int j = tid; j < E2G; j += 256) {
        int d = (j < EPG) ? (sd_s[j] >> 6) : (j - EPG);
        unsigned key = emax_s[d];
        float mx = __uint_as_float((key & 0x80000000u) ? (key & 0x7fffffffu) : ~key);
        atomicAdd(&den_s[d], expf(e_s[j] - mx));
    }
    __syncthreads();

    // P2: pooled aggregate over all edges (mean-pool commutes with segment_sum)
    float acc0 = 0.f, acc1 = 0.f;
    for (int j = wave; j < E2G; j += 4) {
        int s, d;
        if (j < EPG) { int sd = sd_s[j]; s = sd & 63; d = sd >> 6; }
        else { s = d = j - EPG; }
        unsigned key = emax_s[d];
        float mx = __uint_as_float((key & 0x80000000u) ? (key & 0x7fffffffu) : ~key);
        float alpha = expf(e_s[j] - mx) / den_s[d];
        acc0 += alpha * xl_s[s * NCH + lane];
        acc1 += alpha * xl_s[s * NCH + lane + 64];
    }
    gacc_s[wave * NCH + lane] = acc0;
    gacc_s[wave * NCH + lane + 64] = acc1;
    __syncthreads();

    for (int c = tid; c < NCH; c += 256) {
        float v = (gacc_s[c] + gacc_s[NCH + c] + gacc_s[2 * NCH + c] + gacc_s[3 * NCH + c])
                      * (1.f / NNODES) + bias_out[c];
        g_all[(size_t)g * NCH + c] = v;
    }
}

// ---------------- gx_all = g_all @ W_ih^T + b_ih ----------------
__global__ void k_gx(const float* __restrict__ g_all, const float* __restrict__ W_ihT,
                     const float* __restrict__ b_ih, float* __restrict__ gx_all) {
    int idx = blockIdx.x * blockDim.x + threadIdx.x;   // over 800*768
    if (idx >= NGRAPH * 3 * NH) return;
    int gi = idx / (3 * NH);
    int o = idx - gi * (3 * NH);
    float acc = b_ih[o];
    const float* grow = g_all + (size_t)gi * NCH;
    for (int c = 0; c < NCH; ++c) acc += grow[c] * W_ihT[c * (3 * NH) + o];
    gx_all[idx] = acc;
}

// ---------------- GRU (sequential only; h_t stored for parallel classifier) ----------------
// 768 threads = 4 k-groups x 192 threads; thread computes 4 consecutive gh outputs
// over 64 k values with coalesced float4 loads of W_hhT; partials reduced in LDS.
__launch_bounds__(768)
__global__ void k_gru(const float* __restrict__ gx_all, const float* __restrict__ W_hhT,
                      const float* __restrict__ b_hh, float* __restrict__ h_all) {
    __shared__ float h_s[NH];
    __shared__ float part_s[4 * 3 * NH];   // [kg][768]

    const int b = blockIdx.x;
    const int tid = threadIdx.x;
    const int kg = tid / 192;              // 0..3
    const int o4 = (tid - kg * 192) * 4;   // output base 0..764
    const int kbase = kg * 64;
    const float* Wp = W_hhT + (size_t)kbase * (3 * NH) + o4;

    if (tid < NH) h_s[tid] = 0.f;
    __syncthreads();

    for (int t = 0; t < NT; ++t) {
        float a0 = 0.f, a1 = 0.f, a2 = 0.f, a3 = 0.f;
        #pragma unroll 16
        for (int k = 0; k < 64; ++k) {
            float hv = h_s[kbase + k];
            float4 w = *reinterpret_cast<const float4*>(Wp + (size_t)k * (3 * NH));
            a0 += hv * w.x; a1 += hv * w.y; a2 += hv * w.z; a3 += hv * w.w;
        }
        *reinterpret_cast<float4*>(part_s + kg * (3 * NH) + o4) = make_float4(a0, a1, a2, a3);
        __syncthreads();

        if (tid < NH) {
            const float* gx = gx_all + (size_t)(b * NT + t) * (3 * NH);
            float ghr = b_hh[tid];
            float ghz = b_hh[tid + NH];
            float ghn = b_hh[tid + 2 * NH];
            #pragma unroll
            for (int q = 0; q < 4; ++q) {
                ghr += part_s[q * (3 * NH) + tid];
                ghz += part_s[q * (3 * NH) + tid + NH];
                ghn += part_s[q * (3 * NH) + tid + 2 * NH];
            }
            float r = 1.f / (1.f + expf(-(gx[tid] + ghr)));
            float z = 1.f / (1.f + expf(-(gx[tid + NH] + ghz)));
            float n = tanhf(gx[tid + 2 * NH] + r * ghn);
            float hv = (1.f - z) * n + z * h_s[tid];
            h_s[tid] = hv;                                   // only owner thread touches [tid]
            h_all[(size_t)(b * NT + t) * NH + tid] = hv;
        }
        __syncthreads();
    }
}

// ---------------- classifier: scores[b,t,:] = relu(h @ W1 + b1) @ W2 + b2 ----------------
__launch_bounds__(128)
__global__ void k_cls(const float* __restrict__ h_all,
                      const float* __restrict__ W1, const float* __restrict__ b1,
                      const float* __restrict__ W2, const float* __restrict__ b2,
                      float* __restrict__ sc_all) {
    __shared__ float h_s[NH];
    __shared__ float s1_s[NH / 2];
    const int bt = blockIdx.x;
    const int tid = threadIdx.x;
    h_s[tid] = h_all[(size_t)bt * NH + tid];
    h_s[tid + 128] = h_all[(size_t)bt * NH + tid + 128];
    __syncthreads();
    float acc = b1[tid];
    #pragma unroll 8
    for (int k = 0; k < NH; ++k) acc += h_s[k] * W1[k * (NH / 2) + tid];
    s1_s[tid] = fmaxf(acc, 0.f);
    __syncthreads();
    if (tid < NCLS) {
        float a = b2[tid];
        for (int k = 0; k < NH / 2; ++k) a += s1_s[k] * W2[k * NCLS + tid];
        sc_all[bt * NCLS + tid] = a;
    }
}

// ---------------- top-k over time per (b, class) ----------------
__global__ void k_topk(const float* __restrict__ sc_all, float* __restrict__ out) {
    int tid = threadIdx.x;
    if (tid >= NB * NCLS) return;
    int b = tid / NCLS;
    int c = tid - b * NCLS;
    float vals[NT];
    for (int t = 0; t < NT; ++t) vals[t] = sc_all[(b * NT + t) * NCLS + c];
    float sum = 0.f;
    for (int k = 0; k < NTOPK; ++k) {
        float best = -INFINITY; int bi = 0;
        for (int t = 0; t < NT; ++t) {
            if (vals[t] > best) { best = vals[t]; bi = t; }
        }
        vals[bi] = -INFINITY;
        sum += best;
        out[NB * NCLS + b * (NTOPK * NCLS) + k * NCLS + c] = (float)bi;
    }
    out[b * NCLS + c] = sum * (1.f / NTOPK);
}

extern "C" void kernel_launch(void* const* d_in, const int* in_sizes, int n_in,
                              void* d_out, int out_size, void* d_ws, size_t ws_size,
                              hipStream_t stream) {
    const float* x        = (const float*)d_in[0];
    const int*   ei       = (const int*)  d_in[1];
    const float* eattr    = (const float*)d_in[2];
    const float* W_l      = (const float*)d_in[3];
    const float* b_l      = (const float*)d_in[4];
    const float* W_r      = (const float*)d_in[5];
    const float* b_r      = (const float*)d_in[6];
    const float* W_e      = (const float*)d_in[7];
    const float* att      = (const float*)d_in[8];
    const float* bias_out = (const float*)d_in[9];
    const float* W_ih     = (const float*)d_in[10];
    const float* W_hh     = (const float*)d_in[11];
    const float* b_ih     = (const float*)d_in[12];
    const float* b_hh     = (const float*)d_in[13];
    const float* W1       = (const float*)d_in[14];
    const float* b1       = (const float*)d_in[15];
    const float* W2       = (const float*)d_in[16];
    const float* b2       = (const float*)d_in[17];
    float* out = (float*)d_out;

    float* ws = (float*)d_ws;
    float* xr_all = ws;                                   // 49600*128
    float* g_all  = xr_all + (size_t)NTOTAL * NCH;        // 800*128
    float* gx_all = g_all + NGRAPH * NCH;                 // 800*768
    float* W_ihT  = gx_all + NGRAPH * 3 * NH;             // 128*768
    float* W_hhT  = W_ihT + NCH * 3 * NH;                 // 256*768
    float* h_all  = W_hhT + NH * 3 * NH;                  // 800*256
    float* sc_all = h_all + (size_t)NGRAPH * NH;          // 800*3

    int total_xr = NTOTAL * 32;
    k_xr<<<(total_xr + 255) / 256, 256, 0, stream>>>(x, W_r, b_r, xr_all);
    k_transpose<<<(3 * NH * NCH + 255) / 256, 256, 0, stream>>>(W_ih, W_ihT, 3 * NH, NCH);
    k_transpose<<<(3 * NH * NH + 255) / 256, 256, 0, stream>>>(W_hh, W_hhT, 3 * NH, NH);
    k_gat<<<NGRAPH, 256, 0, stream>>>(x, ei, eattr, W_l, b_l, W_e, att, bias_out, xr_all, g_all);
    k_gx<<<(NGRAPH * 3 * NH + 255) / 256, 256, 0, stream>>>(g_all, W_ihT, b_ih, gx_all);
    k_gru<<<NB, 768, 0, stream>>>(gx_all, W_hhT, b_hh, h_all);
    k_cls<<<NB * NT, 128, 0, stream>>>(h_all, W1, b1, W2, b2, sc_all);
    k_topk<<<1, 64, 0, stream>>>(sc_all, out);
}

// Round 3
// 561.824 us; speedup vs baseline: 1.6038x; 1.1559x over previous
//
#include <hip/hip_runtime.h>
#include <math.h>

#define NNODES 62
#define NDEG 8
#define NGRAPH 800
#define NB 16
#define NT 50
#define NIN 64
#define NCH 128
#define NH 256
#define NCLS 3
#define NTOPK 5
#define NKG 4                   // split-k factor for GRU
#define EPG (NNODES*NDEG)       // 496 edges per graph
#define E2G (EPG + NNODES)      // 558 incl self loops
#define NTOTAL (NGRAPH*NNODES)  // 49600
#define ETOTAL (NGRAPH*EPG)     // 396800

// ---------------- xr = x @ W_r + b_r (thread computes 4 consecutive channels) ----------------
__global__ void k_xr(const float* __restrict__ x, const float* __restrict__ W_r,
                     const float* __restrict__ b_r, float* __restrict__ xr) {
    int idx = blockIdx.x * blockDim.x + threadIdx.x;   // over NTOTAL*32
    if (idx >= NTOTAL * 32) return;
    int v = idx >> 5;
    int c4 = (idx & 31) * 4;
    const float* xrow = x + (size_t)v * NIN;
    float4 acc = make_float4(b_r[c4], b_r[c4 + 1], b_r[c4 + 2], b_r[c4 + 3]);
    for (int k = 0; k < NIN; ++k) {
        float xv = xrow[k];
        float4 w = *reinterpret_cast<const float4*>(W_r + k * NCH + c4);
        acc.x += xv * w.x; acc.y += xv * w.y; acc.z += xv * w.z; acc.w += xv * w.w;
    }
    *reinterpret_cast<float4*>(xr + (size_t)v * NCH + c4) = acc;
}

// ---------------- simple transpose ----------------
__global__ void k_transpose(const float* __restrict__ src, float* __restrict__ dst,
                            int rows, int cols) {
    int idx = blockIdx.x * blockDim.x + threadIdx.x;
    if (idx >= rows * cols) return;
    int r = idx / cols;
    int c = idx - r * cols;
    dst[c * rows + r] = src[idx];
}

// ---------------- fused per-graph GATv2 + mean pool ----------------
__launch_bounds__(256)
__global__ void k_gat(const float* __restrict__ x, const int* __restrict__ ei,
                      const float* __restrict__ eattr,
                      const float* __restrict__ W_l, const float* __restrict__ b_l,
                      const float* __restrict__ W_e, const float* __restrict__ att,
                      const float* __restrict__ bias_out,
                      const float* __restrict__ xr_all, float* __restrict__ g_all) {
    __shared__ float x_s[NNODES * NIN];       // 15872 B
    __shared__ float xl_s[NNODES * NCH];      // 31744 B
    __shared__ float e_s[E2G];                // 2232 B
    __shared__ unsigned emax_s[NNODES];
    __shared__ float den_s[NNODES];
    __shared__ float la_s[NNODES];
    __shared__ float cnt_s[NNODES];
    __shared__ float sum_s[NNODES];
    __shared__ unsigned short sd_s[EPG];      // src | dst<<6
    __shared__ float attr_s[EPG];
    __shared__ float gacc_s[4 * NCH];         // per-wave pooled accumulators

    const int g = blockIdx.x;
    const int tid = threadIdx.x;
    const int base_e = g * EPG;
    const int base_n = g * NNODES;

    for (int v = tid; v < NNODES; v += 256) {
        sum_s[v] = 0.f; cnt_s[v] = 0.f; emax_s[v] = 0u; den_s[v] = 0.f;
    }
    for (int j = tid; j < EPG; j += 256) {
        int s = ei[base_e + j] - base_n;
        int d = ei[ETOTAL + base_e + j] - base_n;
        sd_s[j] = (unsigned short)(s | (d << 6));
        attr_s[j] = eattr[base_e + j];
    }
    for (int i = tid; i < NNODES * NIN; i += 256) x_s[i] = x[(size_t)base_n * NIN + i];
    __syncthreads();

    // self-loop edge_attr = mean of incoming edge_attr
    for (int j = tid; j < EPG; j += 256) {
        int d = sd_s[j] >> 6;
        atomicAdd(&sum_s[d], attr_s[j]);
        atomicAdd(&cnt_s[d], 1.f);
    }
    __syncthreads();
    for (int v = tid; v < NNODES; v += 256) la_s[v] = sum_s[v] / fmaxf(cnt_s[v], 1.f);

    // xl = x @ W_l + b_l (in LDS)
    for (int i = tid; i < NNODES * NCH; i += 256) {
        int v = i >> 7;
        int c = i & (NCH - 1);
        float acc = b_l[c];
        const float* xrow = x_s + v * NIN;
        for (int k = 0; k < NIN; ++k) acc += xrow[k] * W_l[k * NCH + c];
        xl_s[i] = acc;
    }
    __syncthreads();

    const int wave = tid >> 6;
    const int lane = tid & 63;

    // P1: per-edge attention logits e, running max per dst (ordered-uint atomicMax)
    for (int j = wave; j < E2G; j += 4) {
        int s, d; float a;
        if (j < EPG) { int sd = sd_s[j]; s = sd & 63; d = sd >> 6; a = attr_s[j]; }
        else { s = d = j - EPG; a = la_s[s]; }
        const float* xrrow = xr_all + (size_t)(base_n + d) * NCH;
        int c0 = lane, c1 = lane + 64;
        float m0 = xl_s[s * NCH + c0] + xrrow[c0] + a * W_e[c0];
        float m1 = xl_s[s * NCH + c1] + xrrow[c1] + a * W_e[c1];
        float t = (m0 >= 0.f ? m0 : 0.2f * m0) * att[c0]
                + (m1 >= 0.f ? m1 : 0.2f * m1) * att[c1];
        for (int off = 32; off > 0; off >>= 1) t += __shfl_xor(t, off, 64);
        if (lane == 0) {
            e_s[j] = t;
            unsigned u = __float_as_uint(t);
            unsigned key = (u & 0x80000000u) ? ~u : (u | 0x80000000u);
            atomicMax(&emax_s[d], key);
        }
    }
    __syncthreads();

    // denominator of scatter-softmax
    for (int j = tid; j < E2G; j += 256) {
        int d = (j < EPG) ? (sd_s[j] >> 6) : (j - EPG);
        unsigned key = emax_s[d];
        float mx = __uint_as_float((key & 0x80000000u) ? (key & 0x7fffffffu) : ~key);
        atomicAdd(&den_s[d], expf(e_s[j] - mx));
    }
    __syncthreads();

    // P2: pooled aggregate over all edges (mean-pool commutes with segment_sum)
    float acc0 = 0.f, acc1 = 0.f;
    for (int j = wave; j < E2G; j += 4) {
        int s, d;
        if (j < EPG) { int sd = sd_s[j]; s = sd & 63; d = sd >> 6; }
        else { s = d = j - EPG; }
        unsigned key = emax_s[d];
        float mx = __uint_as_float((key & 0x80000000u) ? (key & 0x7fffffffu) : ~key);
        float alpha = expf(e_s[j] - mx) / den_s[d];
        acc0 += alpha * xl_s[s * NCH + lane];
        acc1 += alpha * xl_s[s * NCH + lane + 64];
    }
    gacc_s[wave * NCH + lane] = acc0;
    gacc_s[wave * NCH + lane + 64] = acc1;
    __syncthreads();

    for (int c = tid; c < NCH; c += 256) {
        float v = (gacc_s[c] + gacc_s[NCH + c] + gacc_s[2 * NCH + c] + gacc_s[3 * NCH + c])
                      * (1.f / NNODES) + bias_out[c];
        g_all[(size_t)g * NCH + c] = v;
    }
}

// ---------------- gx_all = g_all @ W_ih^T + b_ih (+ b_hh folded for r,z gates) ----------------
__global__ void k_gx(const float* __restrict__ g_all, const float* __restrict__ W_ihT,
                     const float* __restrict__ b_ih, const float* __restrict__ b_hh,
                     float* __restrict__ gx_all) {
    int idx = blockIdx.x * blockDim.x + threadIdx.x;   // over 800*768
    if (idx >= NGRAPH * 3 * NH) return;
    int gi = idx / (3 * NH);
    int o = idx - gi * (3 * NH);
    float acc = b_ih[o] + (o < 2 * NH ? b_hh[o] : 0.f);  // n-gate b_hh stays separate (scaled by r)
    const float* grow = g_all + (size_t)gi * NCH;
    for (int c = 0; c < NCH; ++c) acc += grow[c] * W_ihT[c * (3 * NH) + o];
    gx_all[idx] = acc;
}

// ---------------- zero the GRU sync flags (must precede k_gru each launch) ----------------
__global__ void k_init(unsigned* __restrict__ flags) {
    flags[threadIdx.x] = 0u;
}

// ---------------- GRU: 4-way split-k, 64 blocks, all-to-all partial exchange ----------------
// Block (b,kg) streams only its 64-k quarter of W_hhT (192 KB/step, under the ~64 B/clk
// per-CU L1 cap). Partials exchanged through L3 via agent-scope RELAXED atomics (no
// acquire-invalidate -> W stays L2-hot). Every block redundantly computes the gate update,
// summing partials in fixed kg order => bitwise-identical h across the 4 blocks.
__launch_bounds__(768)
__global__ void k_gru(const float* __restrict__ gx_all, const float* __restrict__ W_hhT,
                      const float* __restrict__ b_hh, float* __restrict__ h_all,
                      float* part, unsigned* flags) {
    __shared__ float h_s[NH];
    __shared__ float gh_s[3 * NH];

    const int bid = blockIdx.x;
    const int b = bid & (NB - 1);
    const int kg = bid >> 4;
    const int o = threadIdx.x;          // output index 0..767
    const int kq0 = kg * 64;
    const float* Wq = W_hhT + (size_t)kq0 * (3 * NH) + o;

    const float bhn = (o < NH) ? b_hh[2 * NH + o] : 0.f;   // n-gate hidden bias (scaled by r)

    if (o < NH) h_s[o] = 0.f;
    __syncthreads();

    for (int t = 0; t < NT; ++t) {
        const int par = t & 1;
        // partial gh over this block's k-quarter
        float acc = 0.f;
        #pragma unroll 8
        for (int k = 0; k < 64; ++k)
            acc += Wq[(size_t)k * (3 * NH)] * h_s[kq0 + k];

        // publish own partial (relaxed agent atomics bypass L1/L2 -> L3-coherent)
        __hip_atomic_store(&part[(((size_t)b * NKG + kg) * 2 + par) * (3 * NH) + o], acc,
                           __ATOMIC_RELAXED, __HIP_MEMORY_SCOPE_AGENT);
        __syncthreads();   // every wave drains its own stores (vmcnt 0 before s_barrier)
        if (o == 0)
            __hip_atomic_store(&flags[b * NKG + kg], (unsigned)(t + 1),
                               __ATOMIC_RELEASE, __HIP_MEMORY_SCOPE_AGENT);

        // wait for the 3 peers (parallel polls, threads 0..2)
        if (o < NKG - 1) {
            int q = o + (o >= kg ? 1 : 0);
            while (__hip_atomic_load(&flags[b * NKG + q], __ATOMIC_RELAXED,
                                     __HIP_MEMORY_SCOPE_AGENT) < (unsigned)(t + 1))
                __builtin_amdgcn_s_sleep(1);
        }
        __syncthreads();
        __atomic_signal_fence(__ATOMIC_ACQUIRE);

        // gather partials in FIXED kg order -> bitwise-identical h on all 4 blocks
        float gh = 0.f;
        #pragma unroll
        for (int q = 0; q < NKG; ++q) {
            float p = (q == kg) ? acc
                    : __hip_atomic_load(&part[(((size_t)b * NKG + q) * 2 + par) * (3 * NH) + o],
                                        __ATOMIC_RELAXED, __HIP_MEMORY_SCOPE_AGENT);
            gh += p;
        }
        gh_s[o] = gh;
        __syncthreads();

        if (o < NH) {
            const float* gx = gx_all + (size_t)(b * NT + t) * (3 * NH);
            float r = 1.f / (1.f + expf(-(gx[o] + gh_s[o])));
            float z = 1.f / (1.f + expf(-(gx[o + NH] + gh_s[o + NH])));
            float n = tanhf(gx[o + 2 * NH] + r * (gh_s[o + 2 * NH] + bhn));
            float hv = (1.f - z) * n + z * h_s[o];
            h_s[o] = hv;
            if (kg == 0) h_all[(size_t)(b * NT + t) * NH + o] = hv;
        }
        __syncthreads();
    }
}

// ---------------- classifier: scores[b,t,:] = relu(h @ W1 + b1) @ W2 + b2 ----------------
__launch_bounds__(128)
__global__ void k_cls(const float* __restrict__ h_all,
                      const float* __restrict__ W1, const float* __restrict__ b1,
                      const float* __restrict__ W2, const float* __restrict__ b2,
                      float* __restrict__ sc_all) {
    __shared__ float h_s[NH];
    __shared__ float s1_s[NH / 2];
    const int bt = blockIdx.x;
    const int tid = threadIdx.x;
    h_s[tid] = h_all[(size_t)bt * NH + tid];
    h_s[tid + 128] = h_all[(size_t)bt * NH + tid + 128];
    __syncthreads();
    float acc = b1[tid];
    #pragma unroll 8
    for (int k = 0; k < NH; ++k) acc += h_s[k] * W1[k * (NH / 2) + tid];
    s1_s[tid] = fmaxf(acc, 0.f);
    __syncthreads();
    if (tid < NCLS) {
        float a = b2[tid];
        for (int k = 0; k < NH / 2; ++k) a += s1_s[k] * W2[k * NCLS + tid];
        sc_all[bt * NCLS + tid] = a;
    }
}

// ---------------- top-k over time per (b, class) ----------------
__global__ void k_topk(const float* __restrict__ sc_all, float* __restrict__ out) {
    int tid = threadIdx.x;
    if (tid >= NB * NCLS) return;
    int b = tid / NCLS;
    int c = tid - b * NCLS;
    float vals[NT];
    for (int t = 0; t < NT; ++t) vals[t] = sc_all[(b * NT + t) * NCLS + c];
    float sum = 0.f;
    for (int k = 0; k < NTOPK; ++k) {
        float best = -INFINITY; int bi = 0;
        for (int t = 0; t < NT; ++t) {
            if (vals[t] > best) { best = vals[t]; bi = t; }
        }
        vals[bi] = -INFINITY;
        sum += best;
        out[NB * NCLS + b * (NTOPK * NCLS) + k * NCLS + c] = (float)bi;
    }
    out[b * NCLS + c] = sum * (1.f / NTOPK);
}

extern "C" void kernel_launch(void* const* d_in, const int* in_sizes, int n_in,
                              void* d_out, int out_size, void* d_ws, size_t ws_size,
                              hipStream_t stream) {
    const float* x        = (const float*)d_in[0];
    const int*   ei       = (const int*)  d_in[1];
    const float* eattr    = (const float*)d_in[2];
    const float* W_l      = (const float*)d_in[3];
    const float* b_l      = (const float*)d_in[4];
    const float* W_r      = (const float*)d_in[5];
    const float* b_r      = (const float*)d_in[6];
    const float* W_e      = (const float*)d_in[7];
    const float* att      = (const float*)d_in[8];
    const float* bias_out = (const float*)d_in[9];
    const float* W_ih     = (const float*)d_in[10];
    const float* W_hh     = (const float*)d_in[11];
    const float* b_ih     = (const float*)d_in[12];
    const float* b_hh     = (const float*)d_in[13];
    const float* W1       = (const float*)d_in[14];
    const float* b1       = (const float*)d_in[15];
    const float* W2       = (const float*)d_in[16];
    const float* b2       = (const float*)d_in[17];
    float* out = (float*)d_out;

    float* ws = (float*)d_ws;
    float* xr_all = ws;                                   // 49600*128 (dead after k_gat)
    float* g_all  = xr_all + (size_t)NTOTAL * NCH;        // 800*128
    float* gx_all = g_all + NGRAPH * NCH;                 // 800*768
    float* W_ihT  = gx_all + NGRAPH * 3 * NH;             // 128*768
    float* W_hhT  = W_ihT + NCH * 3 * NH;                 // 256*768
    float* h_all  = W_hhT + NH * 3 * NH;                  // 800*256
    float* sc_all = h_all + (size_t)NGRAPH * NH;          // 800*3
    // GRU sync buffers alias the front of xr_all (consumed before k_gru runs)
    float*    part  = xr_all;                             // 16*4*2*768 floats
    unsigned* flags = (unsigned*)(xr_all + (size_t)NB * NKG * 2 * 3 * NH);  // 64 u32

    int total_xr = NTOTAL * 32;
    k_xr<<<(total_xr + 255) / 256, 256, 0, stream>>>(x, W_r, b_r, xr_all);
    k_transpose<<<(3 * NH * NCH + 255) / 256, 256, 0, stream>>>(W_ih, W_ihT, 3 * NH, NCH);
    k_transpose<<<(3 * NH * NH + 255) / 256, 256, 0, stream>>>(W_hh, W_hhT, 3 * NH, NH);
    k_gat<<<NGRAPH, 256, 0, stream>>>(x, ei, eattr, W_l, b_l, W_e, att, bias_out, xr_all, g_all);
    k_gx<<<(NGRAPH * 3 * NH + 255) / 256, 256, 0, stream>>>(g_all, W_ihT, b_ih, b_hh, gx_all);
    k_init<<<1, NB * NKG, 0, stream>>>(flags);
    k_gru<<<NB * NKG, 768, 0, stream>>>(gx_all, W_hhT, b_hh, h_all, part, flags);
    k_cls<<<NB * NT, 128, 0, stream>>>(h_all, W1, b1, W2, b2, sc_all);
    k_topk<<<1, 64, 0, stream>>>(sc_all, out);
}

// Round 4
// 419.069 us; speedup vs baseline: 2.1501x; 1.3406x over previous
//
#include <hip/hip_runtime.h>
#include <math.h>

#define NNODES 62
#define NDEG 8
#define NGRAPH 800
#define NB 16
#define NT 50
#define NIN 64
#define NCH 128
#define NH 256
#define NCLS 3
#define NTOPK 5
#define NKG 4                   // split-k factor for GRU
#define EPG (NNODES*NDEG)       // 496 edges per graph
#define E2G (EPG + NNODES)      // 558 incl self loops
#define NTOTAL (NGRAPH*NNODES)  // 49600
#define ETOTAL (NGRAPH*EPG)     // 396800

// ---------------- xr = x@W_r + b_r AND xl = x@W_l + b_l (shared x reads) ----------------
__global__ void k_xrl(const float* __restrict__ x,
                      const float* __restrict__ W_r, const float* __restrict__ b_r,
                      const float* __restrict__ W_l, const float* __restrict__ b_l,
                      float* __restrict__ xr, float* __restrict__ xl) {
    int idx = blockIdx.x * blockDim.x + threadIdx.x;   // over NTOTAL*32
    if (idx >= NTOTAL * 32) return;
    int v = idx >> 5;
    int c4 = (idx & 31) * 4;
    const float* xrow = x + (size_t)v * NIN;
    float4 ar = make_float4(b_r[c4], b_r[c4 + 1], b_r[c4 + 2], b_r[c4 + 3]);
    float4 al = make_float4(b_l[c4], b_l[c4 + 1], b_l[c4 + 2], b_l[c4 + 3]);
    for (int k = 0; k < NIN; ++k) {
        float xv = xrow[k];
        float4 wr = *reinterpret_cast<const float4*>(W_r + k * NCH + c4);
        float4 wl = *reinterpret_cast<const float4*>(W_l + k * NCH + c4);
        ar.x += xv * wr.x; ar.y += xv * wr.y; ar.z += xv * wr.z; ar.w += xv * wr.w;
        al.x += xv * wl.x; al.y += xv * wl.y; al.z += xv * wl.z; al.w += xv * wl.w;
    }
    *reinterpret_cast<float4*>(xr + (size_t)v * NCH + c4) = ar;
    *reinterpret_cast<float4*>(xl + (size_t)v * NCH + c4) = al;
}

// ---------------- simple transpose ----------------
__global__ void k_transpose(const float* __restrict__ src, float* __restrict__ dst,
                            int rows, int cols) {
    int idx = blockIdx.x * blockDim.x + threadIdx.x;
    if (idx >= rows * cols) return;
    int r = idx / cols;
    int c = idx - r * cols;
    dst[c * rows + r] = src[idx];
}

// ---------------- fused per-graph GATv2 + mean pool (edges only; xl precomputed) ----------
// 4 edges per wave: 16 lanes x 8 channels each. LDS ~39.3 KB -> 4 blocks/CU.
__launch_bounds__(256, 4)
__global__ void k_gat(const int* __restrict__ ei, const float* __restrict__ eattr,
                      const float* __restrict__ W_e, const float* __restrict__ att,
                      const float* __restrict__ bias_out,
                      const float* __restrict__ xr_all, const float* __restrict__ xl_all,
                      float* __restrict__ g_all) {
    __shared__ float xl_s[NNODES * NCH];      // 31744 B
    __shared__ float e_s[E2G];                // 2232 B (logits, then exp(e-max))
    __shared__ unsigned emax_s[NNODES];
    __shared__ float den_s[NNODES];           // denom, then 1/denom
    __shared__ float la_s[NNODES];
    __shared__ float cnt_s[NNODES];
    __shared__ float sum_s[NNODES];
    __shared__ unsigned short sd_s[EPG];      // src | dst<<6
    __shared__ float attr_s[EPG];
    __shared__ float gacc_s[4 * NCH];         // per-wave pooled partials

    const int g = blockIdx.x;
    const int tid = threadIdx.x;
    const int base_e = g * EPG;
    const int base_n = g * NNODES;

    for (int v = tid; v < NNODES; v += 256) {
        sum_s[v] = 0.f; cnt_s[v] = 0.f; emax_s[v] = 0u; den_s[v] = 0.f;
    }
    for (int j = tid; j < EPG; j += 256) {
        int s = ei[base_e + j] - base_n;
        int d = ei[ETOTAL + base_e + j] - base_n;
        sd_s[j] = (unsigned short)(s | (d << 6));
        attr_s[j] = eattr[base_e + j];
    }
    // stage xl rows for this graph (coalesced float4)
    {
        const float4* src = reinterpret_cast<const float4*>(xl_all + (size_t)base_n * NCH);
        float4* dst = reinterpret_cast<float4*>(xl_s);
        for (int i = tid; i < NNODES * NCH / 4; i += 256) dst[i] = src[i];
    }
    __syncthreads();

    // self-loop edge_attr = mean of incoming edge_attr
    for (int j = tid; j < EPG; j += 256) {
        int d = sd_s[j] >> 6;
        atomicAdd(&sum_s[d], attr_s[j]);
        atomicAdd(&cnt_s[d], 1.f);
    }
    __syncthreads();
    for (int v = tid; v < NNODES; v += 256) la_s[v] = sum_s[v] / fmaxf(cnt_s[v], 1.f);
    __syncthreads();

    const int wave = tid >> 6;
    const int lane = tid & 63;
    const int grp = lane >> 4;          // edge slot within wave (0..3)
    const int cb = (lane & 15) * 8;     // channel base for this lane

    // hoisted per-lane channel constants
    float we0[8], at0[8];
    #pragma unroll
    for (int i = 0; i < 8; ++i) { we0[i] = W_e[cb + i]; at0[i] = att[cb + i]; }

    // P1: attention logits, 4 edges/wave, 16-lane tree reduce
    for (int j = wave * 4 + grp; j < E2G; j += 16) {
        int s, d; float a;
        if (j < EPG) { int sd = sd_s[j]; s = sd & 63; d = sd >> 6; a = attr_s[j]; }
        else { s = d = j - EPG; a = la_s[s]; }
        float4 xl0 = *reinterpret_cast<const float4*>(&xl_s[s * NCH + cb]);
        float4 xl1 = *reinterpret_cast<const float4*>(&xl_s[s * NCH + cb + 4]);
        const float* xrp = xr_all + (size_t)(base_n + d) * NCH + cb;
        float4 xr0 = *reinterpret_cast<const float4*>(xrp);
        float4 xr1 = *reinterpret_cast<const float4*>(xrp + 4);
        float m[8] = {xl0.x + xr0.x, xl0.y + xr0.y, xl0.z + xr0.z, xl0.w + xr0.w,
                      xl1.x + xr1.x, xl1.y + xr1.y, xl1.z + xr1.z, xl1.w + xr1.w};
        float t = 0.f;
        #pragma unroll
        for (int i = 0; i < 8; ++i) {
            float mi = m[i] + a * we0[i];
            t += (mi >= 0.f ? mi : 0.2f * mi) * at0[i];
        }
        t += __shfl_xor(t, 1, 64);
        t += __shfl_xor(t, 2, 64);
        t += __shfl_xor(t, 4, 64);
        t += __shfl_xor(t, 8, 64);
        if ((lane & 15) == 0) {
            e_s[j] = t;
            unsigned u = __float_as_uint(t);
            unsigned key = (u & 0x80000000u) ? ~u : (u | 0x80000000u);
            atomicMax(&emax_s[d], key);
        }
    }
    __syncthreads();

    // softmax numerator in place + denominator
    for (int j = tid; j < E2G; j += 256) {
        int d = (j < EPG) ? (sd_s[j] >> 6) : (j - EPG);
        unsigned key = emax_s[d];
        float mx = __uint_as_float((key & 0x80000000u) ? (key & 0x7fffffffu) : ~key);
        float ez = expf(e_s[j] - mx);
        e_s[j] = ez;
        atomicAdd(&den_s[d], ez);
    }
    __syncthreads();
    for (int v = tid; v < NNODES; v += 256) den_s[v] = 1.f / den_s[v];
    __syncthreads();

    // P2: pooled aggregate, 4 edges/wave, 8 channels/lane
    float acc[8];
    #pragma unroll
    for (int i = 0; i < 8; ++i) acc[i] = 0.f;
    for (int j = wave * 4 + grp; j < E2G; j += 16) {
        int s, d;
        if (j < EPG) { int sd = sd_s[j]; s = sd & 63; d = sd >> 6; }
        else { s = d = j - EPG; }
        float alpha = e_s[j] * den_s[d];
        float4 x0 = *reinterpret_cast<const float4*>(&xl_s[s * NCH + cb]);
        float4 x1 = *reinterpret_cast<const float4*>(&xl_s[s * NCH + cb + 4]);
        acc[0] += alpha * x0.x; acc[1] += alpha * x0.y;
        acc[2] += alpha * x0.z; acc[3] += alpha * x0.w;
        acc[4] += alpha * x1.x; acc[5] += alpha * x1.y;
        acc[6] += alpha * x1.z; acc[7] += alpha * x1.w;
    }
    // combine the 4 edge-groups (lanes with equal lane&15 hold the same channels)
    #pragma unroll
    for (int i = 0; i < 8; ++i) {
        acc[i] += __shfl_xor(acc[i], 16, 64);
        acc[i] += __shfl_xor(acc[i], 32, 64);
    }
    if (grp == 0) {
        *reinterpret_cast<float4*>(&gacc_s[wave * NCH + cb]) =
            make_float4(acc[0], acc[1], acc[2], acc[3]);
        *reinterpret_cast<float4*>(&gacc_s[wave * NCH + cb + 4]) =
            make_float4(acc[4], acc[5], acc[6], acc[7]);
    }
    __syncthreads();

    for (int c = tid; c < NCH; c += 256) {
        float v = (gacc_s[c] + gacc_s[NCH + c] + gacc_s[2 * NCH + c] + gacc_s[3 * NCH + c])
                      * (1.f / NNODES) + bias_out[c];
        g_all[(size_t)g * NCH + c] = v;
    }
}

// ---------------- gx_all = g_all @ W_ih^T + b_ih (+ b_hh folded for r,z gates) ----------------
__global__ void k_gx(const float* __restrict__ g_all, const float* __restrict__ W_ihT,
                     const float* __restrict__ b_ih, const float* __restrict__ b_hh,
                     float* __restrict__ gx_all) {
    int idx = blockIdx.x * blockDim.x + threadIdx.x;   // over 800*768
    if (idx >= NGRAPH * 3 * NH) return;
    int gi = idx / (3 * NH);
    int o = idx - gi * (3 * NH);
    float acc = b_ih[o] + (o < 2 * NH ? b_hh[o] : 0.f);  // n-gate b_hh stays separate (scaled by r)
    const float* grow = g_all + (size_t)gi * NCH;
    for (int c = 0; c < NCH; ++c) acc += grow[c] * W_ihT[c * (3 * NH) + o];
    gx_all[idx] = acc;
}

// ---------------- zero the GRU sync flags (must precede k_gru each launch) ----------------
__global__ void k_init(unsigned* __restrict__ flags) {
    flags[threadIdx.x] = 0u;
}

// ---------------- GRU: 4-way split-k, 64 blocks, all-to-all partial exchange ----------------
__launch_bounds__(768)
__global__ void k_gru(const float* __restrict__ gx_all, const float* __restrict__ W_hhT,
                      const float* __restrict__ b_hh, float* __restrict__ h_all,
                      float* part, unsigned* flags) {
    __shared__ float h_s[NH];
    __shared__ float gh_s[3 * NH];

    const int bid = blockIdx.x;
    const int b = bid & (NB - 1);
    const int kg = bid >> 4;
    const int o = threadIdx.x;          // output index 0..767
    const int kq0 = kg * 64;
    const float* Wq = W_hhT + (size_t)kq0 * (3 * NH) + o;

    const float bhn = (o < NH) ? b_hh[2 * NH + o] : 0.f;   // n-gate hidden bias (scaled by r)

    if (o < NH) h_s[o] = 0.f;
    __syncthreads();

    for (int t = 0; t < NT; ++t) {
        const int par = t & 1;
        // partial gh over this block's k-quarter
        float acc = 0.f;
        #pragma unroll 8
        for (int k = 0; k < 64; ++k)
            acc += Wq[(size_t)k * (3 * NH)] * h_s[kq0 + k];

        // publish own partial (relaxed agent atomics bypass L1/L2 -> L3-coherent)
        __hip_atomic_store(&part[(((size_t)b * NKG + kg) * 2 + par) * (3 * NH) + o], acc,
                           __ATOMIC_RELAXED, __HIP_MEMORY_SCOPE_AGENT);
        __syncthreads();   // every wave drains its own stores before the flag
        if (o == 0)
            __hip_atomic_store(&flags[b * NKG + kg], (unsigned)(t + 1),
                               __ATOMIC_RELEASE, __HIP_MEMORY_SCOPE_AGENT);

        // wait for the 3 peers (parallel polls, threads 0..2)
        if (o < NKG - 1) {
            int q = o + (o >= kg ? 1 : 0);
            while (__hip_atomic_load(&flags[b * NKG + q], __ATOMIC_RELAXED,
                                     __HIP_MEMORY_SCOPE_AGENT) < (unsigned)(t + 1))
                __builtin_amdgcn_s_sleep(1);
        }
        __syncthreads();
        __atomic_signal_fence(__ATOMIC_ACQUIRE);

        // gather partials in FIXED kg order -> bitwise-identical h on all 4 blocks
        float gh = 0.f;
        #pragma unroll
        for (int q = 0; q < NKG; ++q) {
            float p = (q == kg) ? acc
                    : __hip_atomic_load(&part[(((size_t)b * NKG + q) * 2 + par) * (3 * NH) + o],
                                        __ATOMIC_RELAXED, __HIP_MEMORY_SCOPE_AGENT);
            gh += p;
        }
        gh_s[o] = gh;
        __syncthreads();

        if (o < NH) {
            const float* gx = gx_all + (size_t)(b * NT + t) * (3 * NH);
            float r = 1.f / (1.f + expf(-(gx[o] + gh_s[o])));
            float z = 1.f / (1.f + expf(-(gx[o + NH] + gh_s[o + NH])));
            float n = tanhf(gx[o + 2 * NH] + r * (gh_s[o + 2 * NH] + bhn));
            float hv = (1.f - z) * n + z * h_s[o];
            h_s[o] = hv;
            if (kg == 0) h_all[(size_t)(b * NT + t) * NH + o] = hv;
        }
        __syncthreads();
    }
}

// ---------------- classifier: scores[b,t,:] = relu(h @ W1 + b1) @ W2 + b2 ----------------
__launch_bounds__(128)
__global__ void k_cls(const float* __restrict__ h_all,
                      const float* __restrict__ W1, const float* __restrict__ b1,
                      const float* __restrict__ W2, const float* __restrict__ b2,
                      float* __restrict__ sc_all) {
    __shared__ float h_s[NH];
    __shared__ float s1_s[NH / 2];
    const int bt = blockIdx.x;
    const int tid = threadIdx.x;
    h_s[tid] = h_all[(size_t)bt * NH + tid];
    h_s[tid + 128] = h_all[(size_t)bt * NH + tid + 128];
    __syncthreads();
    float acc = b1[tid];
    #pragma unroll 8
    for (int k = 0; k < NH; ++k) acc += h_s[k] * W1[k * (NH / 2) + tid];
    s1_s[tid] = fmaxf(acc, 0.f);
    __syncthreads();
    if (tid < NCLS) {
        float a = b2[tid];
        for (int k = 0; k < NH / 2; ++k) a += s1_s[k] * W2[k * NCLS + tid];
        sc_all[bt * NCLS + tid] = a;
    }
}

// ---------------- top-k over time per (b, class) ----------------
__global__ void k_topk(const float* __restrict__ sc_all, float* __restrict__ out) {
    int tid = threadIdx.x;
    if (tid >= NB * NCLS) return;
    int b = tid / NCLS;
    int c = tid - b * NCLS;
    float vals[NT];
    for (int t = 0; t < NT; ++t) vals[t] = sc_all[(b * NT + t) * NCLS + c];
    float sum = 0.f;
    for (int k = 0; k < NTOPK; ++k) {
        float best = -INFINITY; int bi = 0;
        for (int t = 0; t < NT; ++t) {
            if (vals[t] > best) { best = vals[t]; bi = t; }
        }
        vals[bi] = -INFINITY;
        sum += best;
        out[NB * NCLS + b * (NTOPK * NCLS) + k * NCLS + c] = (float)bi;
    }
    out[b * NCLS + c] = sum * (1.f / NTOPK);
}

extern "C" void kernel_launch(void* const* d_in, const int* in_sizes, int n_in,
                              void* d_out, int out_size, void* d_ws, size_t ws_size,
                              hipStream_t stream) {
    const float* x        = (const float*)d_in[0];
    const int*   ei       = (const int*)  d_in[1];
    const float* eattr    = (const float*)d_in[2];
    const float* W_l      = (const float*)d_in[3];
    const float* b_l      = (const float*)d_in[4];
    const float* W_r      = (const float*)d_in[5];
    const float* b_r      = (const float*)d_in[6];
    const float* W_e      = (const float*)d_in[7];
    const float* att      = (const float*)d_in[8];
    const float* bias_out = (const float*)d_in[9];
    const float* W_ih     = (const float*)d_in[10];
    const float* W_hh     = (const float*)d_in[11];
    const float* b_ih     = (const float*)d_in[12];
    const float* b_hh     = (const float*)d_in[13];
    const float* W1       = (const float*)d_in[14];
    const float* b1       = (const float*)d_in[15];
    const float* W2       = (const float*)d_in[16];
    const float* b2       = (const float*)d_in[17];
    float* out = (float*)d_out;

    float* ws = (float*)d_ws;
    float* xr_all = ws;                                   // 49600*128 (dead after k_gat)
    float* xl_all = xr_all + (size_t)NTOTAL * NCH;        // 49600*128 (dead after k_gat)
    float* g_all  = xl_all + (size_t)NTOTAL * NCH;        // 800*128
    float* gx_all = g_all + NGRAPH * NCH;                 // 800*768
    float* W_ihT  = gx_all + NGRAPH * 3 * NH;             // 128*768
    float* W_hhT  = W_ihT + NCH * 3 * NH;                 // 256*768
    float* h_all  = W_hhT + NH * 3 * NH;                  // 800*256
    float* sc_all = h_all + (size_t)NGRAPH * NH;          // 800*3
    // GRU sync buffers alias the front of xr_all (consumed before k_gru runs)
    float*    part  = xr_all;                             // 16*4*2*768 floats
    unsigned* flags = (unsigned*)(xr_all + (size_t)NB * NKG * 2 * 3 * NH);  // 64 u32

    int total_xr = NTOTAL * 32;
    k_xrl<<<(total_xr + 255) / 256, 256, 0, stream>>>(x, W_r, b_r, W_l, b_l, xr_all, xl_all);
    k_transpose<<<(3 * NH * NCH + 255) / 256, 256, 0, stream>>>(W_ih, W_ihT, 3 * NH, NCH);
    k_transpose<<<(3 * NH * NH + 255) / 256, 256, 0, stream>>>(W_hh, W_hhT, 3 * NH, NH);
    k_gat<<<NGRAPH, 256, 0, stream>>>(ei, eattr, W_e, att, bias_out, xr_all, xl_all, g_all);
    k_gx<<<(NGRAPH * 3 * NH + 255) / 256, 256, 0, stream>>>(g_all, W_ihT, b_ih, b_hh, gx_all);
    k_init<<<1, NB * NKG, 0, stream>>>(flags);
    k_gru<<<NB * NKG, 768, 0, stream>>>(gx_all, W_hhT, b_hh, h_all, part, flags);
    k_cls<<<NB * NT, 128, 0, stream>>>(h_all, W1, b1, W2, b2, sc_all);
    k_topk<<<1, 64, 0, stream>>>(sc_all, out);
}

// Round 5
// 276.757 us; speedup vs baseline: 3.2557x; 1.5142x over previous
//
#include <hip/hip_runtime.h>
#include <math.h>

#define NNODES 62
#define NDEG 8
#define NGRAPH 800
#define NB 16
#define NT 50
#define NIN 64
#define NCH 128
#define NH 256
#define NCLS 3
#define NTOPK 5
#define NSL 16                  // h-slices per batch (blocks per sequence)
#define EPG (NNODES*NDEG)       // 496 edges per graph
#define E2G (EPG + NNODES)      // 558 incl self loops
#define NTOTAL (NGRAPH*NNODES)  // 49600
#define ETOTAL (NGRAPH*EPG)     // 396800

// ---------------- xr = x@W_r + b_r AND xl = x@W_l + b_l (shared x reads) ----------------
__global__ void k_xrl(const float* __restrict__ x,
                      const float* __restrict__ W_r, const float* __restrict__ b_r,
                      const float* __restrict__ W_l, const float* __restrict__ b_l,
                      float* __restrict__ xr, float* __restrict__ xl) {
    int idx = blockIdx.x * blockDim.x + threadIdx.x;   // over NTOTAL*32
    if (idx >= NTOTAL * 32) return;
    int v = idx >> 5;
    int c4 = (idx & 31) * 4;
    const float* xrow = x + (size_t)v * NIN;
    float4 ar = make_float4(b_r[c4], b_r[c4 + 1], b_r[c4 + 2], b_r[c4 + 3]);
    float4 al = make_float4(b_l[c4], b_l[c4 + 1], b_l[c4 + 2], b_l[c4 + 3]);
    for (int k = 0; k < NIN; ++k) {
        float xv = xrow[k];
        float4 wr = *reinterpret_cast<const float4*>(W_r + k * NCH + c4);
        float4 wl = *reinterpret_cast<const float4*>(W_l + k * NCH + c4);
        ar.x += xv * wr.x; ar.y += xv * wr.y; ar.z += xv * wr.z; ar.w += xv * wr.w;
        al.x += xv * wl.x; al.y += xv * wl.y; al.z += xv * wl.z; al.w += xv * wl.w;
    }
    *reinterpret_cast<float4*>(xr + (size_t)v * NCH + c4) = ar;
    *reinterpret_cast<float4*>(xl + (size_t)v * NCH + c4) = al;
}

// ---------------- simple transpose ----------------
__global__ void k_transpose(const float* __restrict__ src, float* __restrict__ dst,
                            int rows, int cols) {
    int idx = blockIdx.x * blockDim.x + threadIdx.x;
    if (idx >= rows * cols) return;
    int r = idx / cols;
    int c = idx - r * cols;
    dst[c * rows + r] = src[idx];
}

// ---------------- fused per-graph GATv2 + mean pool (edges only; xl precomputed) ----------
__launch_bounds__(256, 4)
__global__ void k_gat(const int* __restrict__ ei, const float* __restrict__ eattr,
                      const float* __restrict__ W_e, const float* __restrict__ att,
                      const float* __restrict__ bias_out,
                      const float* __restrict__ xr_all, const float* __restrict__ xl_all,
                      float* __restrict__ g_all) {
    __shared__ float xl_s[NNODES * NCH];      // 31744 B
    __shared__ float e_s[E2G];                // logits, then exp(e-max)
    __shared__ unsigned emax_s[NNODES];
    __shared__ float den_s[NNODES];           // denom, then 1/denom
    __shared__ float la_s[NNODES];
    __shared__ float cnt_s[NNODES];
    __shared__ float sum_s[NNODES];
    __shared__ unsigned short sd_s[EPG];      // src | dst<<6
    __shared__ float attr_s[EPG];
    __shared__ float gacc_s[4 * NCH];         // per-wave pooled partials

    const int g = blockIdx.x;
    const int tid = threadIdx.x;
    const int base_e = g * EPG;
    const int base_n = g * NNODES;

    for (int v = tid; v < NNODES; v += 256) {
        sum_s[v] = 0.f; cnt_s[v] = 0.f; emax_s[v] = 0u; den_s[v] = 0.f;
    }
    for (int j = tid; j < EPG; j += 256) {
        int s = ei[base_e + j] - base_n;
        int d = ei[ETOTAL + base_e + j] - base_n;
        sd_s[j] = (unsigned short)(s | (d << 6));
        attr_s[j] = eattr[base_e + j];
    }
    {
        const float4* src = reinterpret_cast<const float4*>(xl_all + (size_t)base_n * NCH);
        float4* dst = reinterpret_cast<float4*>(xl_s);
        for (int i = tid; i < NNODES * NCH / 4; i += 256) dst[i] = src[i];
    }
    __syncthreads();

    for (int j = tid; j < EPG; j += 256) {
        int d = sd_s[j] >> 6;
        atomicAdd(&sum_s[d], attr_s[j]);
        atomicAdd(&cnt_s[d], 1.f);
    }
    __syncthreads();
    for (int v = tid; v < NNODES; v += 256) la_s[v] = sum_s[v] / fmaxf(cnt_s[v], 1.f);
    __syncthreads();

    const int wave = tid >> 6;
    const int lane = tid & 63;
    const int grp = lane >> 4;          // edge slot within wave (0..3)
    const int cb = (lane & 15) * 8;     // channel base for this lane

    float we0[8], at0[8];
    #pragma unroll
    for (int i = 0; i < 8; ++i) { we0[i] = W_e[cb + i]; at0[i] = att[cb + i]; }

    // P1: attention logits, 4 edges/wave, 16-lane tree reduce
    for (int j = wave * 4 + grp; j < E2G; j += 16) {
        int s, d; float a;
        if (j < EPG) { int sd = sd_s[j]; s = sd & 63; d = sd >> 6; a = attr_s[j]; }
        else { s = d = j - EPG; a = la_s[s]; }
        float4 xl0 = *reinterpret_cast<const float4*>(&xl_s[s * NCH + cb]);
        float4 xl1 = *reinterpret_cast<const float4*>(&xl_s[s * NCH + cb + 4]);
        const float* xrp = xr_all + (size_t)(base_n + d) * NCH + cb;
        float4 xr0 = *reinterpret_cast<const float4*>(xrp);
        float4 xr1 = *reinterpret_cast<const float4*>(xrp + 4);
        float m[8] = {xl0.x + xr0.x, xl0.y + xr0.y, xl0.z + xr0.z, xl0.w + xr0.w,
                      xl1.x + xr1.x, xl1.y + xr1.y, xl1.z + xr1.z, xl1.w + xr1.w};
        float t = 0.f;
        #pragma unroll
        for (int i = 0; i < 8; ++i) {
            float mi = m[i] + a * we0[i];
            t += (mi >= 0.f ? mi : 0.2f * mi) * at0[i];
        }
        t += __shfl_xor(t, 1, 64);
        t += __shfl_xor(t, 2, 64);
        t += __shfl_xor(t, 4, 64);
        t += __shfl_xor(t, 8, 64);
        if ((lane & 15) == 0) {
            e_s[j] = t;
            unsigned u = __float_as_uint(t);
            unsigned key = (u & 0x80000000u) ? ~u : (u | 0x80000000u);
            atomicMax(&emax_s[d], key);
        }
    }
    __syncthreads();

    for (int j = tid; j < E2G; j += 256) {
        int d = (j < EPG) ? (sd_s[j] >> 6) : (j - EPG);
        unsigned key = emax_s[d];
        float mx = __uint_as_float((key & 0x80000000u) ? (key & 0x7fffffffu) : ~key);
        float ez = expf(e_s[j] - mx);
        e_s[j] = ez;
        atomicAdd(&den_s[d], ez);
    }
    __syncthreads();
    for (int v = tid; v < NNODES; v += 256) den_s[v] = 1.f / den_s[v];
    __syncthreads();

    float acc[8];
    #pragma unroll
    for (int i = 0; i < 8; ++i) acc[i] = 0.f;
    for (int j = wave * 4 + grp; j < E2G; j += 16) {
        int s, d;
        if (j < EPG) { int sd = sd_s[j]; s = sd & 63; d = sd >> 6; }
        else { s = d = j - EPG; }
        float alpha = e_s[j] * den_s[d];
        float4 x0 = *reinterpret_cast<const float4*>(&xl_s[s * NCH + cb]);
        float4 x1 = *reinterpret_cast<const float4*>(&xl_s[s * NCH + cb + 4]);
        acc[0] += alpha * x0.x; acc[1] += alpha * x0.y;
        acc[2] += alpha * x0.z; acc[3] += alpha * x0.w;
        acc[4] += alpha * x1.x; acc[5] += alpha * x1.y;
        acc[6] += alpha * x1.z; acc[7] += alpha * x1.w;
    }
    #pragma unroll
    for (int i = 0; i < 8; ++i) {
        acc[i] += __shfl_xor(acc[i], 16, 64);
        acc[i] += __shfl_xor(acc[i], 32, 64);
    }
    if (grp == 0) {
        *reinterpret_cast<float4*>(&gacc_s[wave * NCH + cb]) =
            make_float4(acc[0], acc[1], acc[2], acc[3]);
        *reinterpret_cast<float4*>(&gacc_s[wave * NCH + cb + 4]) =
            make_float4(acc[4], acc[5], acc[6], acc[7]);
    }
    __syncthreads();

    for (int c = tid; c < NCH; c += 256) {
        float v = (gacc_s[c] + gacc_s[NCH + c] + gacc_s[2 * NCH + c] + gacc_s[3 * NCH + c])
                      * (1.f / NNODES) + bias_out[c];
        g_all[(size_t)g * NCH + c] = v;
    }
}

// ---------------- gx_all = g_all @ W_ih^T + b_ih (+ b_hh folded for r,z gates) ----------------
__global__ void k_gx(const float* __restrict__ g_all, const float* __restrict__ W_ihT,
                     const float* __restrict__ b_ih, const float* __restrict__ b_hh,
                     float* __restrict__ gx_all) {
    int idx = blockIdx.x * blockDim.x + threadIdx.x;   // over 800*768
    if (idx >= NGRAPH * 3 * NH) return;
    int gi = idx / (3 * NH);
    int o = idx - gi * (3 * NH);
    float acc = b_ih[o] + (o < 2 * NH ? b_hh[o] : 0.f);  // n-gate b_hh stays separate (scaled by r)
    const float* grow = g_all + (size_t)gi * NCH;
    for (int c = 0; c < NCH; ++c) acc += grow[c] * W_ihT[c * (3 * NH) + o];
    gx_all[idx] = acc;
}

// ---------------- zero the packed h-exchange buffer (each launch; replay-safe) ------------
__global__ void k_init(unsigned long long* __restrict__ h_pub) {
    int b = blockIdx.x;
    h_pub[((size_t)b * 2 + 0) * NH + threadIdx.x] = 0ull;
    h_pub[((size_t)b * 2 + 1) * NH + threadIdx.x] = 0ull;
}

// ---------------- GRU: 256 blocks (16 batch x 16 slice), W_hh register-resident -----------
// Block (b,s) owns h[16s..16s+15]; its 48 W_hh rows live in VGPRs (4 lanes/row, 64 f/lane).
// Exchange: packed (epoch<<32|float) words through L3 via relaxed agent atomics; peers poll
// the data word itself (single round trip, no flags). Parity double-buffer; k_init zeroes.
__launch_bounds__(256)
__global__ void k_gru(const float* __restrict__ gx_all, const float* __restrict__ W_hh,
                      const float* __restrict__ b_hh, float* __restrict__ h_all,
                      unsigned long long* __restrict__ h_pub) {
    __shared__ __align__(16) float h_s[NH];
    __shared__ float gh_s[48];
    __shared__ float gx_s[2][48];

    const int bid = blockIdx.x;
    const int b = bid >> 4;
    const int s = bid & 15;
    const int tid = threadIdx.x;
    const int wv = tid >> 6;
    const int g = tid >> 2;          // row 0..47 (tid<192)
    const int l = tid & 3;           // k-quarter within row

    // register-resident W rows: row g covers [r|z|n] x 16 outputs of this slice
    float4 Wv[16];
    if (tid < 192) {
        int row = (g < 16) ? (NSL * s + g)
                : (g < 32) ? (NH + NSL * s + (g - 16))
                           : (2 * NH + NSL * s + (g - 32));
        const float* wr = W_hh + (size_t)row * NH + 64 * l;
        #pragma unroll
        for (int j = 0; j < 16; ++j) {
            int jeff = (j + 2 * l) & 15;           // bank-stagger (conflict-free h reads)
            Wv[j] = *reinterpret_cast<const float4*>(wr + 4 * jeff);
        }
    }
    const float bhn = (tid < NSL) ? b_hh[2 * NH + NSL * s + tid] : 0.f;
    const int own_lo = NSL * s, own_hi = NSL * s + NSL;

    for (int i = tid; i < NH; i += 256) h_s[i] = 0.f;
    // prologue gx stage for t=0
    if (wv == 3) {
        int i = tid - 192;
        if (i < 48) {
            int o = (i < 16) ? (NSL * s + i) : (i < 32) ? (NH + NSL * s + i - 16)
                                                        : (2 * NH + NSL * s + i - 32);
            gx_s[0][i] = gx_all[(size_t)(b * NT + 0) * (3 * NH) + o];
        }
    }
    __syncthreads();

    for (int t = 0; t < NT; ++t) {
        if (wv == 3) {
            // stage gx for t+1 (consumed next iteration -> latency fully hidden)
            int i = tid - 192;
            if (i < 48 && t + 1 < NT) {
                int o = (i < 16) ? (NSL * s + i) : (i < 32) ? (NH + NSL * s + i - 16)
                                                            : (2 * NH + NSL * s + i - 32);
                gx_s[(t + 1) & 1][i] = gx_all[(size_t)(b * NT + t + 1) * (3 * NH) + o];
            }
        } else {
            // gh partial: 16 x (ds_read_b128 + 4 fma), staggered -> conflict-free broadcast
            float a0 = 0.f, a1 = 0.f, a2 = 0.f, a3 = 0.f;
            #pragma unroll
            for (int j = 0; j < 16; ++j) {
                int jeff = (j + 2 * l) & 15;
                float4 hv = *reinterpret_cast<const float4*>(&h_s[64 * l + 4 * jeff]);
                float4 w = Wv[j];
                a0 += w.x * hv.x; a1 += w.y * hv.y; a2 += w.z * hv.z; a3 += w.w * hv.w;
            }
            float acc = (a0 + a1) + (a2 + a3);
            acc += __shfl_xor(acc, 1, 64);
            acc += __shfl_xor(acc, 2, 64);
            if (l == 0) gh_s[g] = acc;
        }
        __syncthreads();

        const int par = (t + 1) & 1;
        if (tid < NSL) {
            const float* gx = gx_s[t & 1];
            float r = 1.f / (1.f + expf(-(gx[tid] + gh_s[tid])));
            float z = 1.f / (1.f + expf(-(gx[16 + tid] + gh_s[16 + tid])));
            float n = tanhf(gx[32 + tid] + r * (gh_s[32 + tid] + bhn));
            int o = own_lo + tid;
            float hv = (1.f - z) * n + z * h_s[o];
            h_all[(size_t)(b * NT + t) * NH + o] = hv;
            unsigned long long w = ((unsigned long long)(unsigned)(t + 1) << 32)
                                 | (unsigned long long)__float_as_uint(hv);
            __hip_atomic_store(&h_pub[((size_t)b * 2 + par) * NH + o], w,
                               __ATOMIC_RELAXED, __HIP_MEMORY_SCOPE_AGENT);
            h_s[o] = hv;   // own slot: updated locally (poll threads skip it)
        }
        // poll peers' packed words for epoch t+1 (data IS the flag)
        if (tid < own_lo || tid >= own_hi) {
            const unsigned long long* p = &h_pub[((size_t)b * 2 + par) * NH + tid];
            unsigned long long w;
            const unsigned target = (unsigned)(t + 1);
            while ((unsigned)((w = __hip_atomic_load(p, __ATOMIC_RELAXED,
                                                     __HIP_MEMORY_SCOPE_AGENT)) >> 32) != target)
                __builtin_amdgcn_s_sleep(1);
            h_s[tid] = __uint_as_float((unsigned)w);
        }
        __syncthreads();
    }
}

// ---------------- classifier: scores[b,t,:] = relu(h @ W1 + b1) @ W2 + b2 ----------------
__launch_bounds__(128)
__global__ void k_cls(const float* __restrict__ h_all,
                      const float* __restrict__ W1, const float* __restrict__ b1,
                      const float* __restrict__ W2, const float* __restrict__ b2,
                      float* __restrict__ sc_all) {
    __shared__ float h_s[NH];
    __shared__ float s1_s[NH / 2];
    const int bt = blockIdx.x;
    const int tid = threadIdx.x;
    h_s[tid] = h_all[(size_t)bt * NH + tid];
    h_s[tid + 128] = h_all[(size_t)bt * NH + tid + 128];
    __syncthreads();
    float acc = b1[tid];
    #pragma unroll 8
    for (int k = 0; k < NH; ++k) acc += h_s[k] * W1[k * (NH / 2) + tid];
    s1_s[tid] = fmaxf(acc, 0.f);
    __syncthreads();
    if (tid < NCLS) {
        float a = b2[tid];
        for (int k = 0; k < NH / 2; ++k) a += s1_s[k] * W2[k * NCLS + tid];
        sc_all[bt * NCLS + tid] = a;
    }
}

// ---------------- top-k over time per (b, class) ----------------
__global__ void k_topk(const float* __restrict__ sc_all, float* __restrict__ out) {
    int tid = threadIdx.x;
    if (tid >= NB * NCLS) return;
    int b = tid / NCLS;
    int c = tid - b * NCLS;
    float vals[NT];
    for (int t = 0; t < NT; ++t) vals[t] = sc_all[(b * NT + t) * NCLS + c];
    float sum = 0.f;
    for (int k = 0; k < NTOPK; ++k) {
        float best = -INFINITY; int bi = 0;
        for (int t = 0; t < NT; ++t) {
            if (vals[t] > best) { best = vals[t]; bi = t; }
        }
        vals[bi] = -INFINITY;
        sum += best;
        out[NB * NCLS + b * (NTOPK * NCLS) + k * NCLS + c] = (float)bi;
    }
    out[b * NCLS + c] = sum * (1.f / NTOPK);
}

extern "C" void kernel_launch(void* const* d_in, const int* in_sizes, int n_in,
                              void* d_out, int out_size, void* d_ws, size_t ws_size,
                              hipStream_t stream) {
    const float* x        = (const float*)d_in[0];
    const int*   ei       = (const int*)  d_in[1];
    const float* eattr    = (const float*)d_in[2];
    const float* W_l      = (const float*)d_in[3];
    const float* b_l      = (const float*)d_in[4];
    const float* W_r      = (const float*)d_in[5];
    const float* b_r      = (const float*)d_in[6];
    const float* W_e      = (const float*)d_in[7];
    const float* att      = (const float*)d_in[8];
    const float* bias_out = (const float*)d_in[9];
    const float* W_ih     = (const float*)d_in[10];
    const float* W_hh     = (const float*)d_in[11];
    const float* b_ih     = (const float*)d_in[12];
    const float* b_hh     = (const float*)d_in[13];
    const float* W1       = (const float*)d_in[14];
    const float* b1       = (const float*)d_in[15];
    const float* W2       = (const float*)d_in[16];
    const float* b2       = (const float*)d_in[17];
    float* out = (float*)d_out;

    float* ws = (float*)d_ws;
    float* xr_all = ws;                                   // 49600*128 (dead after k_gat)
    float* xl_all = xr_all + (size_t)NTOTAL * NCH;        // 49600*128 (dead after k_gat)
    float* g_all  = xl_all + (size_t)NTOTAL * NCH;        // 800*128
    float* gx_all = g_all + NGRAPH * NCH;                 // 800*768
    float* W_ihT  = gx_all + NGRAPH * 3 * NH;             // 128*768
    float* h_all  = W_ihT + NCH * 3 * NH;                 // 800*256
    float* sc_all = h_all + (size_t)NGRAPH * NH;          // 800*3
    // packed h-exchange buffer aliases the (dead) xr_all region
    unsigned long long* h_pub = (unsigned long long*)xr_all;   // 16*2*256 u64 = 64 KB

    int total_xr = NTOTAL * 32;
    k_xrl<<<(total_xr + 255) / 256, 256, 0, stream>>>(x, W_r, b_r, W_l, b_l, xr_all, xl_all);
    k_transpose<<<(3 * NH * NCH + 255) / 256, 256, 0, stream>>>(W_ih, W_ihT, 3 * NH, NCH);
    k_gat<<<NGRAPH, 256, 0, stream>>>(ei, eattr, W_e, att, bias_out, xr_all, xl_all, g_all);
    k_gx<<<(NGRAPH * 3 * NH + 255) / 256, 256, 0, stream>>>(g_all, W_ihT, b_ih, b_hh, gx_all);
    k_init<<<NB, NH, 0, stream>>>(h_pub);
    k_gru<<<NB * NSL, 256, 0, stream>>>(gx_all, W_hh, b_hh, h_all, h_pub);
    k_cls<<<NB * NT, 128, 0, stream>>>(h_all, W1, b1, W2, b2, sc_all);
    k_topk<<<1, 64, 0, stream>>>(sc_all, out);
}

// Round 6
// 240.981 us; speedup vs baseline: 3.7391x; 1.1485x over previous
//
#include <hip/hip_runtime.h>
#include <math.h>

#define NNODES 62
#define NDEG 8
#define NGRAPH 800
#define NB 16
#define NT 50
#define NIN 64
#define NCH 128
#define NH 256
#define NCLS 3
#define NTOPK 5
#define NSL 16                  // h-slices per batch (blocks per sequence)
#define EPG (NNODES*NDEG)       // 496 edges per graph
#define E2G (EPG + NNODES)      // 558 incl self loops
#define NTOTAL (NGRAPH*NNODES)  // 49600
#define ETOTAL (NGRAPH*EPG)     // 396800

// ---------------- xr = x@W_r + b_r AND xl = x@W_l + b_l ----------------
// Block = 64 nodes (775 blocks). Thread: 4 channels x 8 nodes x {r,l} = 64 accumulators.
// Each W float4 load feeds 64 FMAs (8x more reuse than 1-node/thread) -> L1-balanced.
__launch_bounds__(256)
__global__ void k_xrl(const float* __restrict__ x,
                      const float* __restrict__ W_r, const float* __restrict__ b_r,
                      const float* __restrict__ W_l, const float* __restrict__ b_l,
                      float* __restrict__ xr, float* __restrict__ xl) {
    __shared__ __align__(16) float x_s[64 * NIN];   // 16 KB
    const int blk = blockIdx.x;                     // 775 blocks (49600/64)
    const int tid = threadIdx.x;
    const int base_v = blk * 64;

    // stage x tile (64 nodes x 64 k), coalesced float4
    {
        const float4* src = reinterpret_cast<const float4*>(x + (size_t)base_v * NIN);
        float4* dst = reinterpret_cast<float4*>(x_s);
        for (int i = tid; i < 64 * NIN / 4; i += 256) dst[i] = src[i];
    }
    __syncthreads();

    const int c4 = (tid & 31) * 4;
    const int ng = tid >> 5;          // 0..7 -> nodes ng*8 .. ng*8+7
    float4 aR[8], aL[8];
    float4 br4 = *reinterpret_cast<const float4*>(b_r + c4);
    float4 bl4 = *reinterpret_cast<const float4*>(b_l + c4);
    #pragma unroll
    for (int j = 0; j < 8; ++j) { aR[j] = br4; aL[j] = bl4; }

    const float* xs = x_s + (ng * 8) * NIN;
    for (int k4 = 0; k4 < NIN; k4 += 4) {
        float4 xv[8];
        #pragma unroll
        for (int j = 0; j < 8; ++j)
            xv[j] = *reinterpret_cast<const float4*>(&xs[j * NIN + k4]);   // broadcast b128
        #pragma unroll
        for (int kk = 0; kk < 4; ++kk) {
            float4 wr = *reinterpret_cast<const float4*>(W_r + (size_t)(k4 + kk) * NCH + c4);
            float4 wl = *reinterpret_cast<const float4*>(W_l + (size_t)(k4 + kk) * NCH + c4);
            #pragma unroll
            for (int j = 0; j < 8; ++j) {
                float xk = (kk == 0) ? xv[j].x : (kk == 1) ? xv[j].y
                         : (kk == 2) ? xv[j].z : xv[j].w;
                aR[j].x += xk * wr.x; aR[j].y += xk * wr.y;
                aR[j].z += xk * wr.z; aR[j].w += xk * wr.w;
                aL[j].x += xk * wl.x; aL[j].y += xk * wl.y;
                aL[j].z += xk * wl.z; aL[j].w += xk * wl.w;
            }
        }
    }
    #pragma unroll
    for (int j = 0; j < 8; ++j) {
        int v = base_v + ng * 8 + j;
        *reinterpret_cast<float4*>(xr + (size_t)v * NCH + c4) = aR[j];
        *reinterpret_cast<float4*>(xl + (size_t)v * NCH + c4) = aL[j];
    }
}

// ---------------- simple transpose ----------------
__global__ void k_transpose(const float* __restrict__ src, float* __restrict__ dst,
                            int rows, int cols) {
    int idx = blockIdx.x * blockDim.x + threadIdx.x;
    if (idx >= rows * cols) return;
    int r = idx / cols;
    int c = idx - r * cols;
    dst[c * rows + r] = src[idx];
}

// ---------------- fused per-graph GATv2 + mean pool (edges only; xl precomputed) ----------
__launch_bounds__(256, 4)
__global__ void k_gat(const int* __restrict__ ei, const float* __restrict__ eattr,
                      const float* __restrict__ W_e, const float* __restrict__ att,
                      const float* __restrict__ bias_out,
                      const float* __restrict__ xr_all, const float* __restrict__ xl_all,
                      float* __restrict__ g_all) {
    __shared__ float xl_s[NNODES * NCH];      // 31744 B
    __shared__ float e_s[E2G];                // logits, then exp(e-max)
    __shared__ unsigned emax_s[NNODES];
    __shared__ float den_s[NNODES];           // denom, then 1/denom
    __shared__ float la_s[NNODES];
    __shared__ float cnt_s[NNODES];
    __shared__ float sum_s[NNODES];
    __shared__ unsigned short sd_s[EPG];      // src | dst<<6
    __shared__ float attr_s[EPG];
    __shared__ float gacc_s[4 * NCH];         // per-wave pooled partials

    const int g = blockIdx.x;
    const int tid = threadIdx.x;
    const int base_e = g * EPG;
    const int base_n = g * NNODES;

    for (int v = tid; v < NNODES; v += 256) {
        sum_s[v] = 0.f; cnt_s[v] = 0.f; emax_s[v] = 0u; den_s[v] = 0.f;
    }
    for (int j = tid; j < EPG; j += 256) {
        int s = ei[base_e + j] - base_n;
        int d = ei[ETOTAL + base_e + j] - base_n;
        sd_s[j] = (unsigned short)(s | (d << 6));
        attr_s[j] = eattr[base_e + j];
    }
    {
        const float4* src = reinterpret_cast<const float4*>(xl_all + (size_t)base_n * NCH);
        float4* dst = reinterpret_cast<float4*>(xl_s);
        for (int i = tid; i < NNODES * NCH / 4; i += 256) dst[i] = src[i];
    }
    __syncthreads();

    for (int j = tid; j < EPG; j += 256) {
        int d = sd_s[j] >> 6;
        atomicAdd(&sum_s[d], attr_s[j]);
        atomicAdd(&cnt_s[d], 1.f);
    }
    __syncthreads();
    for (int v = tid; v < NNODES; v += 256) la_s[v] = sum_s[v] / fmaxf(cnt_s[v], 1.f);
    __syncthreads();

    const int wave = tid >> 6;
    const int lane = tid & 63;
    const int grp = lane >> 4;          // edge slot within wave (0..3)
    const int cb = (lane & 15) * 8;     // channel base for this lane

    float we0[8], at0[8];
    #pragma unroll
    for (int i = 0; i < 8; ++i) { we0[i] = W_e[cb + i]; at0[i] = att[cb + i]; }

    // P1: attention logits, 4 edges/wave, 16-lane tree reduce
    for (int j = wave * 4 + grp; j < E2G; j += 16) {
        int s, d; float a;
        if (j < EPG) { int sd = sd_s[j]; s = sd & 63; d = sd >> 6; a = attr_s[j]; }
        else { s = d = j - EPG; a = la_s[s]; }
        float4 xl0 = *reinterpret_cast<const float4*>(&xl_s[s * NCH + cb]);
        float4 xl1 = *reinterpret_cast<const float4*>(&xl_s[s * NCH + cb + 4]);
        const float* xrp = xr_all + (size_t)(base_n + d) * NCH + cb;
        float4 xr0 = *reinterpret_cast<const float4*>(xrp);
        float4 xr1 = *reinterpret_cast<const float4*>(xrp + 4);
        float m[8] = {xl0.x + xr0.x, xl0.y + xr0.y, xl0.z + xr0.z, xl0.w + xr0.w,
                      xl1.x + xr1.x, xl1.y + xr1.y, xl1.z + xr1.z, xl1.w + xr1.w};
        float t = 0.f;
        #pragma unroll
        for (int i = 0; i < 8; ++i) {
            float mi = m[i] + a * we0[i];
            t += (mi >= 0.f ? mi : 0.2f * mi) * at0[i];
        }
        t += __shfl_xor(t, 1, 64);
        t += __shfl_xor(t, 2, 64);
        t += __shfl_xor(t, 4, 64);
        t += __shfl_xor(t, 8, 64);
        if ((lane & 15) == 0) {
            e_s[j] = t;
            unsigned u = __float_as_uint(t);
            unsigned key = (u & 0x80000000u) ? ~u : (u | 0x80000000u);
            atomicMax(&emax_s[d], key);
        }
    }
    __syncthreads();

    for (int j = tid; j < E2G; j += 256) {
        int d = (j < EPG) ? (sd_s[j] >> 6) : (j - EPG);
        unsigned key = emax_s[d];
        float mx = __uint_as_float((key & 0x80000000u) ? (key & 0x7fffffffu) : ~key);
        float ez = expf(e_s[j] - mx);
        e_s[j] = ez;
        atomicAdd(&den_s[d], ez);
    }
    __syncthreads();
    for (int v = tid; v < NNODES; v += 256) den_s[v] = 1.f / den_s[v];
    __syncthreads();

    float acc[8];
    #pragma unroll
    for (int i = 0; i < 8; ++i) acc[i] = 0.f;
    for (int j = wave * 4 + grp; j < E2G; j += 16) {
        int s, d;
        if (j < EPG) { int sd = sd_s[j]; s = sd & 63; d = sd >> 6; }
        else { s = d = j - EPG; }
        float alpha = e_s[j] * den_s[d];
        float4 x0 = *reinterpret_cast<const float4*>(&xl_s[s * NCH + cb]);
        float4 x1 = *reinterpret_cast<const float4*>(&xl_s[s * NCH + cb + 4]);
        acc[0] += alpha * x0.x; acc[1] += alpha * x0.y;
        acc[2] += alpha * x0.z; acc[3] += alpha * x0.w;
        acc[4] += alpha * x1.x; acc[5] += alpha * x1.y;
        acc[6] += alpha * x1.z; acc[7] += alpha * x1.w;
    }
    #pragma unroll
    for (int i = 0; i < 8; ++i) {
        acc[i] += __shfl_xor(acc[i], 16, 64);
        acc[i] += __shfl_xor(acc[i], 32, 64);
    }
    if (grp == 0) {
        *reinterpret_cast<float4*>(&gacc_s[wave * NCH + cb]) =
            make_float4(acc[0], acc[1], acc[2], acc[3]);
        *reinterpret_cast<float4*>(&gacc_s[wave * NCH + cb + 4]) =
            make_float4(acc[4], acc[5], acc[6], acc[7]);
    }
    __syncthreads();

    for (int c = tid; c < NCH; c += 256) {
        float v = (gacc_s[c] + gacc_s[NCH + c] + gacc_s[2 * NCH + c] + gacc_s[3 * NCH + c])
                      * (1.f / NNODES) + bias_out[c];
        g_all[(size_t)g * NCH + c] = v;
    }
}

// ---------------- gx_all = g_all @ W_ih^T + b_ih (+ b_hh folded for r,z gates) ----------------
__global__ void k_gx(const float* __restrict__ g_all, const float* __restrict__ W_ihT,
                     const float* __restrict__ b_ih, const float* __restrict__ b_hh,
                     float* __restrict__ gx_all) {
    int idx = blockIdx.x * blockDim.x + threadIdx.x;   // over 800*768
    if (idx >= NGRAPH * 3 * NH) return;
    int gi = idx / (3 * NH);
    int o = idx - gi * (3 * NH);
    float acc = b_ih[o] + (o < 2 * NH ? b_hh[o] : 0.f);  // n-gate b_hh stays separate (scaled by r)
    const float* grow = g_all + (size_t)gi * NCH;
    for (int c = 0; c < NCH; ++c) acc += grow[c] * W_ihT[c * (3 * NH) + o];
    gx_all[idx] = acc;
}

// ---------------- zero the packed h-exchange buffer (each launch; replay-safe) ------------
__global__ void k_init(unsigned long long* __restrict__ h_pub) {
    int b = blockIdx.x;
    h_pub[((size_t)b * 2 + 0) * NH + threadIdx.x] = 0ull;
    h_pub[((size_t)b * 2 + 1) * NH + threadIdx.x] = 0ull;
}

// ---------------- GRU: 256 blocks (16 batch x 16 slice), W_hh register-resident -----------
__launch_bounds__(256)
__global__ void k_gru(const float* __restrict__ gx_all, const float* __restrict__ W_hh,
                      const float* __restrict__ b_hh, float* __restrict__ h_all,
                      unsigned long long* __restrict__ h_pub) {
    __shared__ __align__(16) float h_s[NH];
    __shared__ float gh_s[48];
    __shared__ float gx_s[2][48];

    const int bid = blockIdx.x;
    const int b = bid >> 4;
    const int s = bid & 15;
    const int tid = threadIdx.x;
    const int wv = tid >> 6;
    const int g = tid >> 2;          // row 0..47 (tid<192)
    const int l = tid & 3;           // k-quarter within row

    float4 Wv[16];
    if (tid < 192) {
        int row = (g < 16) ? (NSL * s + g)
                : (g < 32) ? (NH + NSL * s + (g - 16))
                           : (2 * NH + NSL * s + (g - 32));
        const float* wr = W_hh + (size_t)row * NH + 64 * l;
        #pragma unroll
        for (int j = 0; j < 16; ++j) {
            int jeff = (j + 2 * l) & 15;           // bank-stagger (conflict-free h reads)
            Wv[j] = *reinterpret_cast<const float4*>(wr + 4 * jeff);
        }
    }
    const float bhn = (tid < NSL) ? b_hh[2 * NH + NSL * s + tid] : 0.f;
    const int own_lo = NSL * s, own_hi = NSL * s + NSL;

    for (int i = tid; i < NH; i += 256) h_s[i] = 0.f;
    if (wv == 3) {
        int i = tid - 192;
        if (i < 48) {
            int o = (i < 16) ? (NSL * s + i) : (i < 32) ? (NH + NSL * s + i - 16)
                                                        : (2 * NH + NSL * s + i - 32);
            gx_s[0][i] = gx_all[(size_t)(b * NT + 0) * (3 * NH) + o];
        }
    }
    __syncthreads();

    for (int t = 0; t < NT; ++t) {
        if (wv == 3) {
            int i = tid - 192;
            if (i < 48 && t + 1 < NT) {
                int o = (i < 16) ? (NSL * s + i) : (i < 32) ? (NH + NSL * s + i - 16)
                                                            : (2 * NH + NSL * s + i - 32);
                gx_s[(t + 1) & 1][i] = gx_all[(size_t)(b * NT + t + 1) * (3 * NH) + o];
            }
        } else {
            float a0 = 0.f, a1 = 0.f, a2 = 0.f, a3 = 0.f;
            #pragma unroll
            for (int j = 0; j < 16; ++j) {
                int jeff = (j + 2 * l) & 15;
                float4 hv = *reinterpret_cast<const float4*>(&h_s[64 * l + 4 * jeff]);
                float4 w = Wv[j];
                a0 += w.x * hv.x; a1 += w.y * hv.y; a2 += w.z * hv.z; a3 += w.w * hv.w;
            }
            float acc = (a0 + a1) + (a2 + a3);
            acc += __shfl_xor(acc, 1, 64);
            acc += __shfl_xor(acc, 2, 64);
            if (l == 0) gh_s[g] = acc;
        }
        __syncthreads();

        const int par = (t + 1) & 1;
        if (tid < NSL) {
            const float* gx = gx_s[t & 1];
            float r = 1.f / (1.f + expf(-(gx[tid] + gh_s[tid])));
            float z = 1.f / (1.f + expf(-(gx[16 + tid] + gh_s[16 + tid])));
            float n = tanhf(gx[32 + tid] + r * (gh_s[32 + tid] + bhn));
            int o = own_lo + tid;
            float hv = (1.f - z) * n + z * h_s[o];
            h_all[(size_t)(b * NT + t) * NH + o] = hv;
            unsigned long long w = ((unsigned long long)(unsigned)(t + 1) << 32)
                                 | (unsigned long long)__float_as_uint(hv);
            __hip_atomic_store(&h_pub[((size_t)b * 2 + par) * NH + o], w,
                               __ATOMIC_RELAXED, __HIP_MEMORY_SCOPE_AGENT);
            h_s[o] = hv;
        }
        if (tid < own_lo || tid >= own_hi) {
            const unsigned long long* p = &h_pub[((size_t)b * 2 + par) * NH + tid];
            unsigned long long w;
            const unsigned target = (unsigned)(t + 1);
            while ((unsigned)((w = __hip_atomic_load(p, __ATOMIC_RELAXED,
                                                     __HIP_MEMORY_SCOPE_AGENT)) >> 32) != target)
                __builtin_amdgcn_s_sleep(1);
            h_s[tid] = __uint_as_float((unsigned)w);
        }
        __syncthreads();
    }
}

// ---------------- classifier: scores[b,t,:] = relu(h @ W1 + b1) @ W2 + b2 ----------------
__launch_bounds__(128)
__global__ void k_cls(const float* __restrict__ h_all,
                      const float* __restrict__ W1, const float* __restrict__ b1,
                      const float* __restrict__ W2, const float* __restrict__ b2,
                      float* __restrict__ sc_all) {
    __shared__ float h_s[NH];
    __shared__ float s1_s[NH / 2];
    const int bt = blockIdx.x;
    const int tid = threadIdx.x;
    h_s[tid] = h_all[(size_t)bt * NH + tid];
    h_s[tid + 128] = h_all[(size_t)bt * NH + tid + 128];
    __syncthreads();
    float acc = b1[tid];
    #pragma unroll 8
    for (int k = 0; k < NH; ++k) acc += h_s[k] * W1[k * (NH / 2) + tid];
    s1_s[tid] = fmaxf(acc, 0.f);
    __syncthreads();
    if (tid < NCLS) {
        float a = b2[tid];
        for (int k = 0; k < NH / 2; ++k) a += s1_s[k] * W2[k * NCLS + tid];
        sc_all[bt * NCLS + tid] = a;
    }
}

// ---------------- top-k over time per (b, class) ----------------
__global__ void k_topk(const float* __restrict__ sc_all, float* __restrict__ out) {
    int tid = threadIdx.x;
    if (tid >= NB * NCLS) return;
    int b = tid / NCLS;
    int c = tid - b * NCLS;
    float vals[NT];
    for (int t = 0; t < NT; ++t) vals[t] = sc_all[(b * NT + t) * NCLS + c];
    float sum = 0.f;
    for (int k = 0; k < NTOPK; ++k) {
        float best = -INFINITY; int bi = 0;
        for (int t = 0; t < NT; ++t) {
            if (vals[t] > best) { best = vals[t]; bi = t; }
        }
        vals[bi] = -INFINITY;
        sum += best;
        out[NB * NCLS + b * (NTOPK * NCLS) + k * NCLS + c] = (float)bi;
    }
    out[b * NCLS + c] = sum * (1.f / NTOPK);
}

extern "C" void kernel_launch(void* const* d_in, const int* in_sizes, int n_in,
                              void* d_out, int out_size, void* d_ws, size_t ws_size,
                              hipStream_t stream) {
    const float* x        = (const float*)d_in[0];
    const int*   ei       = (const int*)  d_in[1];
    const float* eattr    = (const float*)d_in[2];
    const float* W_l      = (const float*)d_in[3];
    const float* b_l      = (const float*)d_in[4];
    const float* W_r      = (const float*)d_in[5];
    const float* b_r      = (const float*)d_in[6];
    const float* W_e      = (const float*)d_in[7];
    const float* att      = (const float*)d_in[8];
    const float* bias_out = (const float*)d_in[9];
    const float* W_ih     = (const float*)d_in[10];
    const float* W_hh     = (const float*)d_in[11];
    const float* b_ih     = (const float*)d_in[12];
    const float* b_hh     = (const float*)d_in[13];
    const float* W1       = (const float*)d_in[14];
    const float* b1       = (const float*)d_in[15];
    const float* W2       = (const float*)d_in[16];
    const float* b2       = (const float*)d_in[17];
    float* out = (float*)d_out;

    float* ws = (float*)d_ws;
    float* xr_all = ws;                                   // 49600*128 (dead after k_gat)
    float* xl_all = xr_all + (size_t)NTOTAL * NCH;        // 49600*128 (dead after k_gat)
    float* g_all  = xl_all + (size_t)NTOTAL * NCH;        // 800*128
    float* gx_all = g_all + NGRAPH * NCH;                 // 800*768
    float* W_ihT  = gx_all + NGRAPH * 3 * NH;             // 128*768
    float* h_all  = W_ihT + NCH * 3 * NH;                 // 800*256
    float* sc_all = h_all + (size_t)NGRAPH * NH;          // 800*3
    unsigned long long* h_pub = (unsigned long long*)xr_all;   // 16*2*256 u64 = 64 KB

    k_xrl<<<NTOTAL / 64, 256, 0, stream>>>(x, W_r, b_r, W_l, b_l, xr_all, xl_all);
    k_transpose<<<(3 * NH * NCH + 255) / 256, 256, 0, stream>>>(W_ih, W_ihT, 3 * NH, NCH);
    k_gat<<<NGRAPH, 256, 0, stream>>>(ei, eattr, W_e, att, bias_out, xr_all, xl_all, g_all);
    k_gx<<<(NGRAPH * 3 * NH + 255) / 256, 256, 0, stream>>>(g_all, W_ihT, b_ih, b_hh, gx_all);
    k_init<<<NB, NH, 0, stream>>>(h_pub);
    k_gru<<<NB * NSL, 256, 0, stream>>>(gx_all, W_hh, b_hh, h_all, h_pub);
    k_cls<<<NB * NT, 128, 0, stream>>>(h_all, W1, b1, W2, b2, sc_all);
    k_topk<<<1, 64, 0, stream>>>(sc_all, out);
}

// Round 7
// 213.863 us; speedup vs baseline: 4.2132x; 1.1268x over previous
//
#include <hip/hip_runtime.h>
#include <math.h>

#define NNODES 62
#define NDEG 8
#define NGRAPH 800
#define NB 16
#define NT 50
#define NIN 64
#define NCH 128
#define NH 256
#define NCLS 3
#define NTOPK 5
#define NSL 16                  // h-slices per batch (blocks per sequence)
#define EPG (NNODES*NDEG)       // 496 edges per graph
#define E2G (EPG + NNODES)      // 558 incl self loops
#define NTOTAL (NGRAPH*NNODES)  // 49600
#define ETOTAL (NGRAPH*EPG)     // 396800

// ---------------- xr = x@W_r + b_r AND xl = x@W_l + b_l ----------------
// Block = 64 nodes. x (16KB) + W_r + W_l (64KB) staged in LDS -> inner loop is pure
// LDS b128 + FMA (no global-latency stalls). 80KB LDS -> 2 blocks/CU.
__launch_bounds__(256, 2)
__global__ void k_xrl(const float* __restrict__ x,
                      const float* __restrict__ W_r, const float* __restrict__ b_r,
                      const float* __restrict__ W_l, const float* __restrict__ b_l,
                      float* __restrict__ xr, float* __restrict__ xl) {
    __shared__ __align__(16) float x_s[64 * NIN];      // 16 KB
    __shared__ __align__(16) float wr_s[NIN * NCH];    // 32 KB
    __shared__ __align__(16) float wl_s[NIN * NCH];    // 32 KB
    const int blk = blockIdx.x;                        // 775 blocks (49600/64)
    const int tid = threadIdx.x;
    const int base_v = blk * 64;

    {
        const float4* src = reinterpret_cast<const float4*>(x + (size_t)base_v * NIN);
        float4* dst = reinterpret_cast<float4*>(x_s);
        for (int i = tid; i < 64 * NIN / 4; i += 256) dst[i] = src[i];
        const float4* sr = reinterpret_cast<const float4*>(W_r);
        const float4* sl = reinterpret_cast<const float4*>(W_l);
        float4* dr = reinterpret_cast<float4*>(wr_s);
        float4* dl = reinterpret_cast<float4*>(wl_s);
        for (int i = tid; i < NIN * NCH / 4; i += 256) { dr[i] = sr[i]; dl[i] = sl[i]; }
    }
    __syncthreads();

    const int c4 = (tid & 31) * 4;
    const int ng = tid >> 5;          // 0..7 -> nodes ng*8 .. ng*8+7
    float4 aR[8], aL[8];
    float4 br4 = *reinterpret_cast<const float4*>(b_r + c4);
    float4 bl4 = *reinterpret_cast<const float4*>(b_l + c4);
    #pragma unroll
    for (int j = 0; j < 8; ++j) { aR[j] = br4; aL[j] = bl4; }

    const float* xs = x_s + (ng * 8) * NIN;
    for (int k4 = 0; k4 < NIN; k4 += 4) {
        float4 xv[8];
        #pragma unroll
        for (int j = 0; j < 8; ++j)
            xv[j] = *reinterpret_cast<const float4*>(&xs[j * NIN + k4]);   // broadcast b128
        #pragma unroll
        for (int kk = 0; kk < 4; ++kk) {
            float4 wr = *reinterpret_cast<const float4*>(&wr_s[(k4 + kk) * NCH + c4]);
            float4 wl = *reinterpret_cast<const float4*>(&wl_s[(k4 + kk) * NCH + c4]);
            #pragma unroll
            for (int j = 0; j < 8; ++j) {
                float xk = (kk == 0) ? xv[j].x : (kk == 1) ? xv[j].y
                         : (kk == 2) ? xv[j].z : xv[j].w;
                aR[j].x += xk * wr.x; aR[j].y += xk * wr.y;
                aR[j].z += xk * wr.z; aR[j].w += xk * wr.w;
                aL[j].x += xk * wl.x; aL[j].y += xk * wl.y;
                aL[j].z += xk * wl.z; aL[j].w += xk * wl.w;
            }
        }
    }
    #pragma unroll
    for (int j = 0; j < 8; ++j) {
        int v = base_v + ng * 8 + j;
        *reinterpret_cast<float4*>(xr + (size_t)v * NCH + c4) = aR[j];
        *reinterpret_cast<float4*>(xl + (size_t)v * NCH + c4) = aL[j];
    }
}

// ---------------- simple transpose ----------------
__global__ void k_transpose(const float* __restrict__ src, float* __restrict__ dst,
                            int rows, int cols) {
    int idx = blockIdx.x * blockDim.x + threadIdx.x;
    if (idx >= rows * cols) return;
    int r = idx / cols;
    int c = idx - r * cols;
    dst[c * rows + r] = src[idx];
}

// ---------------- fused per-graph GATv2 + mean pool (edges only; xl precomputed) ----------
__launch_bounds__(256, 4)
__global__ void k_gat(const int* __restrict__ ei, const float* __restrict__ eattr,
                      const float* __restrict__ W_e, const float* __restrict__ att,
                      const float* __restrict__ bias_out,
                      const float* __restrict__ xr_all, const float* __restrict__ xl_all,
                      float* __restrict__ g_all) {
    __shared__ float xl_s[NNODES * NCH];      // 31744 B
    __shared__ float e_s[E2G];                // logits, then exp(e-max)
    __shared__ unsigned emax_s[NNODES];
    __shared__ float den_s[NNODES];           // denom, then 1/denom
    __shared__ float la_s[NNODES];
    __shared__ float cnt_s[NNODES];
    __shared__ float sum_s[NNODES];
    __shared__ unsigned short sd_s[EPG];      // src | dst<<6
    __shared__ float attr_s[EPG];
    __shared__ float gacc_s[4 * NCH];         // per-wave pooled partials

    const int g = blockIdx.x;
    const int tid = threadIdx.x;
    const int base_e = g * EPG;
    const int base_n = g * NNODES;

    for (int v = tid; v < NNODES; v += 256) {
        sum_s[v] = 0.f; cnt_s[v] = 0.f; emax_s[v] = 0u; den_s[v] = 0.f;
    }
    for (int j = tid; j < EPG; j += 256) {
        int s = ei[base_e + j] - base_n;
        int d = ei[ETOTAL + base_e + j] - base_n;
        sd_s[j] = (unsigned short)(s | (d << 6));
        attr_s[j] = eattr[base_e + j];
    }
    {
        const float4* src = reinterpret_cast<const float4*>(xl_all + (size_t)base_n * NCH);
        float4* dst = reinterpret_cast<float4*>(xl_s);
        for (int i = tid; i < NNODES * NCH / 4; i += 256) dst[i] = src[i];
    }
    __syncthreads();

    for (int j = tid; j < EPG; j += 256) {
        int d = sd_s[j] >> 6;
        atomicAdd(&sum_s[d], attr_s[j]);
        atomicAdd(&cnt_s[d], 1.f);
    }
    __syncthreads();
    for (int v = tid; v < NNODES; v += 256) la_s[v] = sum_s[v] / fmaxf(cnt_s[v], 1.f);
    __syncthreads();

    const int wave = tid >> 6;
    const int lane = tid & 63;
    const int grp = lane >> 4;          // edge slot within wave (0..3)
    const int cb = (lane & 15) * 8;     // channel base for this lane

    float we0[8], at0[8];
    #pragma unroll
    for (int i = 0; i < 8; ++i) { we0[i] = W_e[cb + i]; at0[i] = att[cb + i]; }

    // P1: attention logits, 4 edges/wave, 16-lane tree reduce
    for (int j = wave * 4 + grp; j < E2G; j += 16) {
        int s, d; float a;
        if (j < EPG) { int sd = sd_s[j]; s = sd & 63; d = sd >> 6; a = attr_s[j]; }
        else { s = d = j - EPG; a = la_s[s]; }
        float4 xl0 = *reinterpret_cast<const float4*>(&xl_s[s * NCH + cb]);
        float4 xl1 = *reinterpret_cast<const float4*>(&xl_s[s * NCH + cb + 4]);
        const float* xrp = xr_all + (size_t)(base_n + d) * NCH + cb;
        float4 xr0 = *reinterpret_cast<const float4*>(xrp);
        float4 xr1 = *reinterpret_cast<const float4*>(xrp + 4);
        float m[8] = {xl0.x + xr0.x, xl0.y + xr0.y, xl0.z + xr0.z, xl0.w + xr0.w,
                      xl1.x + xr1.x, xl1.y + xr1.y, xl1.z + xr1.z, xl1.w + xr1.w};
        float t = 0.f;
        #pragma unroll
        for (int i = 0; i < 8; ++i) {
            float mi = m[i] + a * we0[i];
            t += (mi >= 0.f ? mi : 0.2f * mi) * at0[i];
        }
        t += __shfl_xor(t, 1, 64);
        t += __shfl_xor(t, 2, 64);
        t += __shfl_xor(t, 4, 64);
        t += __shfl_xor(t, 8, 64);
        if ((lane & 15) == 0) {
            e_s[j] = t;
            unsigned u = __float_as_uint(t);
            unsigned key = (u & 0x80000000u) ? ~u : (u | 0x80000000u);
            atomicMax(&emax_s[d], key);
        }
    }
    __syncthreads();

    for (int j = tid; j < E2G; j += 256) {
        int d = (j < EPG) ? (sd_s[j] >> 6) : (j - EPG);
        unsigned key = emax_s[d];
        float mx = __uint_as_float((key & 0x80000000u) ? (key & 0x7fffffffu) : ~key);
        float ez = expf(e_s[j] - mx);
        e_s[j] = ez;
        atomicAdd(&den_s[d], ez);
    }
    __syncthreads();
    for (int v = tid; v < NNODES; v += 256) den_s[v] = 1.f / den_s[v];
    __syncthreads();

    float acc[8];
    #pragma unroll
    for (int i = 0; i < 8; ++i) acc[i] = 0.f;
    for (int j = wave * 4 + grp; j < E2G; j += 16) {
        int s, d;
        if (j < EPG) { int sd = sd_s[j]; s = sd & 63; d = sd >> 6; }
        else { s = d = j - EPG; }
        float alpha = e_s[j] * den_s[d];
        float4 x0 = *reinterpret_cast<const float4*>(&xl_s[s * NCH + cb]);
        float4 x1 = *reinterpret_cast<const float4*>(&xl_s[s * NCH + cb + 4]);
        acc[0] += alpha * x0.x; acc[1] += alpha * x0.y;
        acc[2] += alpha * x0.z; acc[3] += alpha * x0.w;
        acc[4] += alpha * x1.x; acc[5] += alpha * x1.y;
        acc[6] += alpha * x1.z; acc[7] += alpha * x1.w;
    }
    #pragma unroll
    for (int i = 0; i < 8; ++i) {
        acc[i] += __shfl_xor(acc[i], 16, 64);
        acc[i] += __shfl_xor(acc[i], 32, 64);
    }
    if (grp == 0) {
        *reinterpret_cast<float4*>(&gacc_s[wave * NCH + cb]) =
            make_float4(acc[0], acc[1], acc[2], acc[3]);
        *reinterpret_cast<float4*>(&gacc_s[wave * NCH + cb + 4]) =
            make_float4(acc[4], acc[5], acc[6], acc[7]);
    }
    __syncthreads();

    for (int c = tid; c < NCH; c += 256) {
        float v = (gacc_s[c] + gacc_s[NCH + c] + gacc_s[2 * NCH + c] + gacc_s[3 * NCH + c])
                      * (1.f / NNODES) + bias_out[c];
        g_all[(size_t)g * NCH + c] = v;
    }
}

// ---------------- gx_all = g_all @ W_ih^T + biases; also zeroes h_pub (replay-safe) ------
__global__ void k_gx(const float* __restrict__ g_all, const float* __restrict__ W_ihT,
                     const float* __restrict__ b_ih, const float* __restrict__ b_hh,
                     float* __restrict__ gx_all, unsigned long long* __restrict__ h_pub) {
    if (blockIdx.x < 32)
        h_pub[(size_t)blockIdx.x * 256 + threadIdx.x] = 0ull;   // 8192 u64 total
    int idx = blockIdx.x * blockDim.x + threadIdx.x;   // over 800*768
    if (idx >= NGRAPH * 3 * NH) return;
    int gi = idx / (3 * NH);
    int o = idx - gi * (3 * NH);
    float acc = b_ih[o] + (o < 2 * NH ? b_hh[o] : 0.f);  // n-gate b_hh stays separate (scaled by r)
    const float* grow = g_all + (size_t)gi * NCH;
    for (int c = 0; c < NCH; ++c) acc += grow[c] * W_ihT[c * (3 * NH) + o];
    gx_all[idx] = acc;
}

// ---------------- GRU: 256 blocks (16 batch x 16 slice), W_hh register-resident -----------
__launch_bounds__(256)
__global__ void k_gru(const float* __restrict__ gx_all, const float* __restrict__ W_hh,
                      const float* __restrict__ b_hh, float* __restrict__ h_all,
                      unsigned long long* __restrict__ h_pub) {
    __shared__ __align__(16) float h_s[NH];
    __shared__ float gh_s[48];
    __shared__ float gx_s[2][48];

    const int bid = blockIdx.x;
    const int b = bid >> 4;
    const int s = bid & 15;
    const int tid = threadIdx.x;
    const int wv = tid >> 6;
    const int g = tid >> 2;          // row 0..47 (tid<192)
    const int l = tid & 3;           // k-quarter within row

    float4 Wv[16];
    if (tid < 192) {
        int row = (g < 16) ? (NSL * s + g)
                : (g < 32) ? (NH + NSL * s + (g - 16))
                           : (2 * NH + NSL * s + (g - 32));
        const float* wr = W_hh + (size_t)row * NH + 64 * l;
        #pragma unroll
        for (int j = 0; j < 16; ++j) {
            int jeff = (j + 2 * l) & 15;           // bank-stagger (conflict-free h reads)
            Wv[j] = *reinterpret_cast<const float4*>(wr + 4 * jeff);
        }
    }
    const float bhn = (tid < NSL) ? b_hh[2 * NH + NSL * s + tid] : 0.f;
    const int own_lo = NSL * s, own_hi = NSL * s + NSL;

    for (int i = tid; i < NH; i += 256) h_s[i] = 0.f;
    if (wv == 3) {
        int i = tid - 192;
        if (i < 48) {
            int o = (i < 16) ? (NSL * s + i) : (i < 32) ? (NH + NSL * s + i - 16)
                                                        : (2 * NH + NSL * s + i - 32);
            gx_s[0][i] = gx_all[(size_t)(b * NT + 0) * (3 * NH) + o];
        }
    }
    __syncthreads();

    for (int t = 0; t < NT; ++t) {
        if (wv == 3) {
            int i = tid - 192;
            if (i < 48 && t + 1 < NT) {
                int o = (i < 16) ? (NSL * s + i) : (i < 32) ? (NH + NSL * s + i - 16)
                                                            : (2 * NH + NSL * s + i - 32);
                gx_s[(t + 1) & 1][i] = gx_all[(size_t)(b * NT + t + 1) * (3 * NH) + o];
            }
        } else {
            float a0 = 0.f, a1 = 0.f, a2 = 0.f, a3 = 0.f;
            #pragma unroll
            for (int j = 0; j < 16; ++j) {
                int jeff = (j + 2 * l) & 15;
                float4 hv = *reinterpret_cast<const float4*>(&h_s[64 * l + 4 * jeff]);
                float4 w = Wv[j];
                a0 += w.x * hv.x; a1 += w.y * hv.y; a2 += w.z * hv.z; a3 += w.w * hv.w;
            }
            float acc = (a0 + a1) + (a2 + a3);
            acc += __shfl_xor(acc, 1, 64);
            acc += __shfl_xor(acc, 2, 64);
            if (l == 0) gh_s[g] = acc;
        }
        __syncthreads();

        const int par = (t + 1) & 1;
        if (tid < NSL) {
            const float* gx = gx_s[t & 1];
            float r = 1.f / (1.f + expf(-(gx[tid] + gh_s[tid])));
            float z = 1.f / (1.f + expf(-(gx[16 + tid] + gh_s[16 + tid])));
            float n = tanhf(gx[32 + tid] + r * (gh_s[32 + tid] + bhn));
            int o = own_lo + tid;
            float hv = (1.f - z) * n + z * h_s[o];
            h_all[(size_t)(b * NT + t) * NH + o] = hv;
            unsigned long long w = ((unsigned long long)(unsigned)(t + 1) << 32)
                                 | (unsigned long long)__float_as_uint(hv);
            __hip_atomic_store(&h_pub[((size_t)b * 2 + par) * NH + o], w,
                               __ATOMIC_RELAXED, __HIP_MEMORY_SCOPE_AGENT);
            h_s[o] = hv;
        }
        if (tid < own_lo || tid >= own_hi) {
            const unsigned long long* p = &h_pub[((size_t)b * 2 + par) * NH + tid];
            unsigned long long w;
            const unsigned target = (unsigned)(t + 1);
            while ((unsigned)((w = __hip_atomic_load(p, __ATOMIC_RELAXED,
                                                     __HIP_MEMORY_SCOPE_AGENT)) >> 32) != target)
                ;   // tight spin: epoch word IS the data, detect ASAP
            h_s[tid] = __uint_as_float((unsigned)w);
        }
        __syncthreads();
    }
}

// ---------------- classifier: scores[b,t,:] = relu(h @ W1 + b1) @ W2 + b2 ----------------
__launch_bounds__(128)
__global__ void k_cls(const float* __restrict__ h_all,
                      const float* __restrict__ W1, const float* __restrict__ b1,
                      const float* __restrict__ W2, const float* __restrict__ b2,
                      float* __restrict__ sc_all) {
    __shared__ float h_s[NH];
    __shared__ float s1_s[NH / 2];
    const int bt = blockIdx.x;
    const int tid = threadIdx.x;
    h_s[tid] = h_all[(size_t)bt * NH + tid];
    h_s[tid + 128] = h_all[(size_t)bt * NH + tid + 128];
    __syncthreads();
    float acc = b1[tid];
    #pragma unroll 8
    for (int k = 0; k < NH; ++k) acc += h_s[k] * W1[k * (NH / 2) + tid];
    s1_s[tid] = fmaxf(acc, 0.f);
    __syncthreads();
    if (tid < NCLS) {
        float a = b2[tid];
        for (int k = 0; k < NH / 2; ++k) a += s1_s[k] * W2[k * NCLS + tid];
        sc_all[bt * NCLS + tid] = a;
    }
}

// ---------------- top-k over time per (b, class) ----------------
__global__ void k_topk(const float* __restrict__ sc_all, float* __restrict__ out) {
    int tid = threadIdx.x;
    if (tid >= NB * NCLS) return;
    int b = tid / NCLS;
    int c = tid - b * NCLS;
    float vals[NT];
    for (int t = 0; t < NT; ++t) vals[t] = sc_all[(b * NT + t) * NCLS + c];
    float sum = 0.f;
    for (int k = 0; k < NTOPK; ++k) {
        float best = -INFINITY; int bi = 0;
        for (int t = 0; t < NT; ++t) {
            if (vals[t] > best) { best = vals[t]; bi = t; }
        }
        vals[bi] = -INFINITY;
        sum += best;
        out[NB * NCLS + b * (NTOPK * NCLS) + k * NCLS + c] = (float)bi;
    }
    out[b * NCLS + c] = sum * (1.f / NTOPK);
}

extern "C" void kernel_launch(void* const* d_in, const int* in_sizes, int n_in,
                              void* d_out, int out_size, void* d_ws, size_t ws_size,
                              hipStream_t stream) {
    const float* x        = (const float*)d_in[0];
    const int*   ei       = (const int*)  d_in[1];
    const float* eattr    = (const float*)d_in[2];
    const float* W_l      = (const float*)d_in[3];
    const float* b_l      = (const float*)d_in[4];
    const float* W_r      = (const float*)d_in[5];
    const float* b_r      = (const float*)d_in[6];
    const float* W_e      = (const float*)d_in[7];
    const float* att      = (const float*)d_in[8];
    const float* bias_out = (const float*)d_in[9];
    const float* W_ih     = (const float*)d_in[10];
    const float* W_hh     = (const float*)d_in[11];
    const float* b_ih     = (const float*)d_in[12];
    const float* b_hh     = (const float*)d_in[13];
    const float* W1       = (const float*)d_in[14];
    const float* b1       = (const float*)d_in[15];
    const float* W2       = (const float*)d_in[16];
    const float* b2       = (const float*)d_in[17];
    float* out = (float*)d_out;

    float* ws = (float*)d_ws;
    float* xr_all = ws;                                   // 49600*128 (dead after k_gat)
    float* xl_all = xr_all + (size_t)NTOTAL * NCH;        // 49600*128 (dead after k_gat)
    float* g_all  = xl_all + (size_t)NTOTAL * NCH;        // 800*128
    float* gx_all = g_all + NGRAPH * NCH;                 // 800*768
    float* W_ihT  = gx_all + NGRAPH * 3 * NH;             // 128*768
    float* h_all  = W_ihT + NCH * 3 * NH;                 // 800*256
    float* sc_all = h_all + (size_t)NGRAPH * NH;          // 800*3
    unsigned long long* h_pub = (unsigned long long*)xr_all;   // 16*2*256 u64 = 64 KB

    k_xrl<<<NTOTAL / 64, 256, 0, stream>>>(x, W_r, b_r, W_l, b_l, xr_all, xl_all);
    k_transpose<<<(3 * NH * NCH + 255) / 256, 256, 0, stream>>>(W_ih, W_ihT, 3 * NH, NCH);
    k_gat<<<NGRAPH, 256, 0, stream>>>(ei, eattr, W_e, att, bias_out, xr_all, xl_all, g_all);
    k_gx<<<(NGRAPH * 3 * NH + 255) / 256, 256, 0, stream>>>(g_all, W_ihT, b_ih, b_hh, gx_all, h_pub);
    k_gru<<<NB * NSL, 256, 0, stream>>>(gx_all, W_hh, b_hh, h_all, h_pub);
    k_cls<<<NB * NT, 128, 0, stream>>>(h_all, W1, b1, W2, b2, sc_all);
    k_topk<<<1, 64, 0, stream>>>(sc_all, out);
}